// Round 10
// baseline (274.737 us; speedup 1.0000x reference)
//
#include <hip/hip_runtime.h>

// B=8, C=64, N=2048, K=32, H=8, d=8. Inputs FLOAT32; output FLOAT32.
// R18: REVERT to the R16-passed kernel (R17's attn+select rewrites failed a
// post-absmax harness check; bug not identifiable -> not kept). Single
// surgical change vs R16: attn es[4][8][32] -> [33]. The serial softmax read
// es[w2][h][j] at addr t*32+j was a 32-way bank conflict (3.08M/dispatch,
// measured R16); stride 33 gives bank (8*w2+h+j)%32, distinct per thread.
// Semantics bit-identical to R16 (no order/mapping changes).

#define NN 2048

typedef __attribute__((ext_vector_type(8))) short bf16x8;
typedef __attribute__((ext_vector_type(8))) unsigned short u16x8;
typedef __attribute__((ext_vector_type(4))) float f32x4;

// Exact 3-way bf16 split of an f32 value (hi+mid+lo == x exactly).
__device__ inline void bsplit(float x, short& h, short& m, short& l)
{
    unsigned u  = __float_as_uint(x);
    unsigned hb = (u + 0x7FFFu + ((u >> 16) & 1u)) >> 16;
    float hf = __uint_as_float(hb << 16);
    float r1 = x - hf;                       // exact (Sterbenz)
    unsigned u1 = __float_as_uint(r1);
    unsigned mb = (u1 + 0x7FFFu + ((u1 >> 16) & 1u)) >> 16;
    float mf = __uint_as_float(mb << 16);
    float r2 = r1 - mf;                      // exact; <= 8 significant bits
    unsigned u2 = __float_as_uint(r2);
    unsigned lb = (u2 + 0x7FFFu + ((u2 >> 16) & 1u)) >> 16;
    h = (short)hb; m = (short)mb; l = (short)lb;
}

// ---------------------------------------------------------------- prep ------
__global__ __launch_bounds__(256) void prep_kernel(
    const float* __restrict__ x, const float* __restrict__ Wk,
    const float* __restrict__ Wv, float* __restrict__ xx,
    float* __restrict__ KT, float* __restrict__ VT,
    short* __restrict__ xh, short* __restrict__ xm, short* __restrict__ xl)
{
    __shared__ float xs[64][33];
    __shared__ float wks[4096], wvs[4096];
    const int t = threadIdx.x;
    const int b = blockIdx.x >> 6;
    const int n0 = (blockIdx.x & 63) * 32;
    for (int i = 0; i < 16; ++i) {
        int e = t + 256 * i;
        wks[e] = Wk[e];
        wvs[e] = Wv[e];
    }
    for (int i = 0; i < 8; ++i) {
        int e = t + 256 * i;
        xs[e >> 5][e & 31] = x[((size_t)b * 64 + (e >> 5)) * 2048 + n0 + (e & 31)];
    }
    __syncthreads();
    if (t < 32) {
        float s = 0.f;
#pragma unroll
        for (int c = 0; c < 64; ++c) { float v = xs[c][t]; s += v * v; }
        xx[b * 2048 + n0 + t] = s;
    }
    const int p = t & 31, g = t >> 5;
    {   // split planes: thread (p,g) -> channels [g*8, g*8+8) of point p
        u16x8 vh, vm, vl;
#pragma unroll
        for (int ci = 0; ci < 8; ++ci) {
            short h, m, l;
            bsplit(xs[g * 8 + ci][p], h, m, l);
            vh[ci] = (unsigned short)h; vm[ci] = (unsigned short)m; vl[ci] = (unsigned short)l;
        }
        size_t base = ((size_t)(b * 2048 + n0 + p)) * 64 + g * 8;
        *reinterpret_cast<u16x8*>(xh + base) = vh;
        *reinterpret_cast<u16x8*>(xm + base) = vm;
        *reinterpret_cast<u16x8*>(xl + base) = vl;
    }
    {   // K/V projections: 8 output channels per thread
        float xv[64];
#pragma unroll
        for (int c = 0; c < 64; ++c) xv[c] = xs[c][p];
        size_t base = ((size_t)(b * 2048 + n0 + p)) * 64 + g * 8;
        float ok[8], ov[8];
#pragma unroll
        for (int oi = 0; oi < 8; ++oi) {
            int o = g * 8 + oi;
            float ak = 0.f, av = 0.f;
#pragma unroll
            for (int c = 0; c < 64; ++c) {
                float xc = xv[c];
                ak += wks[o * 64 + c] * xc;
                av += wvs[o * 64 + c] * xc;
            }
            ok[oi] = ak; ov[oi] = av;
        }
        *reinterpret_cast<float4*>(KT + base)     = make_float4(ok[0], ok[1], ok[2], ok[3]);
        *reinterpret_cast<float4*>(KT + base + 4) = make_float4(ok[4], ok[5], ok[6], ok[7]);
        *reinterpret_cast<float4*>(VT + base)     = make_float4(ov[0], ov[1], ov[2], ov[3]);
        *reinterpret_cast<float4*>(VT + base + 4) = make_float4(ov[4], ov[5], ov[6], ov[7]);
    }
}

// ---------------------------------------------------------------- qproj -----
__global__ __launch_bounds__(256) void qproj_kernel(
    const float* __restrict__ x, const float* __restrict__ Wq,
    float* __restrict__ Qp)
{
    __shared__ float xs[64][33];
    __shared__ float wqs[4096];
    const int t = threadIdx.x;
    const int b = blockIdx.x >> 6;
    const int n0 = (blockIdx.x & 63) * 32;
    for (int i = 0; i < 16; ++i) { int e = t + 256 * i; wqs[e] = Wq[e]; }
    for (int i = 0; i < 8; ++i) {
        int e = t + 256 * i;
        xs[e >> 5][e & 31] = x[((size_t)b * 64 + (e >> 5)) * 2048 + n0 + (e & 31)];
    }
    __syncthreads();
    const int p = t & 31, g = t >> 5;
    float xv[64];
#pragma unroll
    for (int c = 0; c < 64; ++c) xv[c] = xs[c][p];
    size_t base = ((size_t)(b * 2048 + n0 + p)) * 64 + g * 8;
    float oq[8];
#pragma unroll
    for (int oi = 0; oi < 8; ++oi) {
        int o = g * 8 + oi;
        float a = 0.f;
#pragma unroll
        for (int c = 0; c < 64; ++c) a += wqs[o * 64 + c] * xv[c];
        oq[oi] = a * 0.35355339059327379f;
    }
    *reinterpret_cast<float4*>(Qp + base)     = make_float4(oq[0], oq[1], oq[2], oq[3]);
    *reinterpret_cast<float4*>(Qp + base + 4) = make_float4(oq[4], oq[5], oq[6], oq[7]);
}

// ------------------------------------------------------------- knn gemm -----
// D'[b][n][m] = (2*G[n][m] - xx[n]) - xx[m]; sortable u32 key stored as
// hi16 -> Kp, lo16 -> Lp at pos = c0 + rl*8 + cb (col = c0 + cb*16 + rl).
// MFMA order identical to R12: lh,hl,mm,mh,hm,hh.
__device__ inline void mm6(f32x4& a, bf16x8 Ah, bf16x8 Am, bf16x8 Al,
                           bf16x8 Bh, bf16x8 Bm, bf16x8 Bl)
{
    a = __builtin_amdgcn_mfma_f32_16x16x32_bf16(Al, Bh, a, 0, 0, 0);
    a = __builtin_amdgcn_mfma_f32_16x16x32_bf16(Ah, Bl, a, 0, 0, 0);
    a = __builtin_amdgcn_mfma_f32_16x16x32_bf16(Am, Bm, a, 0, 0, 0);
    a = __builtin_amdgcn_mfma_f32_16x16x32_bf16(Am, Bh, a, 0, 0, 0);
    a = __builtin_amdgcn_mfma_f32_16x16x32_bf16(Ah, Bm, a, 0, 0, 0);
    a = __builtin_amdgcn_mfma_f32_16x16x32_bf16(Ah, Bh, a, 0, 0, 0);
}

__global__ __launch_bounds__(256) void gemm_kernel(
    const short* __restrict__ xh, const short* __restrict__ xm,
    const short* __restrict__ xl, const float* __restrict__ xx,
    unsigned short* __restrict__ Kp, unsigned short* __restrict__ Lp)
{
    __shared__ short BhL[8192], BmL[8192], BlL[8192];  // 48 KiB
    const int t = threadIdx.x;
    const int lane = t & 63;
    const int w = t >> 6;
    const int b = blockIdx.x >> 8;
    const int tile = blockIdx.x & 255;
    const int r0 = (tile >> 4) * 128 + w * 32;
    const int c0 = (tile & 15) * 128;
    const int rl = lane & 15;
    const int g = lane >> 4;
    const int kg = g * 8;

    const size_t boff = (size_t)b * 2048 * 64;
    const short* XH = xh + boff;
    const short* XM = xm + boff;
    const short* XL = xl + boff;

    bf16x8 aH[2][2], aM[2][2], aL[2][2];
#pragma unroll
    for (int s = 0; s < 2; ++s)
#pragma unroll
        for (int rb = 0; rb < 2; ++rb) {
            const size_t ab = (size_t)(r0 + rb * 16 + rl) * 64 + s * 32 + kg;
            aH[s][rb] = *reinterpret_cast<const bf16x8*>(XH + ab);
            aM[s][rb] = *reinterpret_cast<const bf16x8*>(XM + ab);
            aL[s][rb] = *reinterpret_cast<const bf16x8*>(XL + ab);
        }

    {   // stage B panel; 16B chunk swizzle j ^= col&7
        const short* sH = XH + (size_t)c0 * 64;
        const short* sM = XM + (size_t)c0 * 64;
        const short* sL = XL + (size_t)c0 * 64;
#pragma unroll
        for (int i = 0; i < 4; ++i) {
            int ci = t + 256 * i;
            int col = ci >> 3, j = ci & 7;
            int d = col * 64 + ((j ^ (col & 7)) << 3);
            *reinterpret_cast<u16x8*>(BhL + d) = *reinterpret_cast<const u16x8*>(sH + ci * 8);
            *reinterpret_cast<u16x8*>(BmL + d) = *reinterpret_cast<const u16x8*>(sM + ci * 8);
            *reinterpret_cast<u16x8*>(BlL + d) = *reinterpret_cast<const u16x8*>(sL + ci * 8);
        }
    }
    __syncthreads();

    f32x4 acc[2][8];
#pragma unroll
    for (int rb = 0; rb < 2; ++rb)
#pragma unroll
        for (int cb = 0; cb < 8; ++cb)
            acc[rb][cb] = (f32x4){0.f, 0.f, 0.f, 0.f};

#pragma unroll
    for (int cb = 0; cb < 8; ++cb) {
        __builtin_amdgcn_sched_barrier(0);
        const int cl = cb * 16 + rl;
#pragma unroll
        for (int s = 0; s < 2; ++s) {
            const int d = cl * 64 + (((s * 4 + g) ^ (cl & 7)) << 3);
            bf16x8 Bh = *reinterpret_cast<const bf16x8*>(BhL + d);
            bf16x8 Bm = *reinterpret_cast<const bf16x8*>(BmL + d);
            bf16x8 Bl = *reinterpret_cast<const bf16x8*>(BlL + d);
            mm6(acc[0][cb], aH[s][0], aM[s][0], aL[s][0], Bh, Bm, Bl);
            mm6(acc[1][cb], aH[s][1], aM[s][1], aL[s][1], Bh, Bm, Bl);
        }
    }
    __builtin_amdgcn_sched_barrier(0);

    // epilogue: C/D layout col=lane&15, row=(lane>>4)*4+reg; store key planes
    const float* xxb = xx + b * 2048;
    const int rg = g * 4;
#pragma unroll
    for (int rb = 0; rb < 2; ++rb) {
#pragma unroll
        for (int e = 0; e < 4; ++e) {
            const int row = r0 + rb * 16 + rg + e;
            const float xn = xxb[row];
            unsigned hiw[4], low[4];
#pragma unroll
            for (int cp = 0; cp < 4; ++cp) {
                unsigned su[2];
#pragma unroll
                for (int h2 = 0; h2 < 2; ++h2) {
                    const int cb = cp * 2 + h2;
                    float v = 2.f * acc[rb][cb][e] - xn;   // (2G - xx_n)
                    v = v - xxb[c0 + cb * 16 + rl];        // ... - xx_m
                    unsigned u = __float_as_uint(v);
                    su[h2] = u ^ (unsigned)(((int)u >> 31) | 0x80000000);
                }
                hiw[cp] = (su[0] >> 16) | (su[1] & 0xFFFF0000u);
                low[cp] = (su[0] & 0xFFFFu) | (su[1] << 16);
            }
            const size_t base = ((size_t)(b * 2048 + row)) * 2048 + c0 + rl * 8;
            *reinterpret_cast<uint4*>(Kp + base) = make_uint4(hiw[0], hiw[1], hiw[2], hiw[3]);
            *reinterpret_cast<uint4*>(Lp + base) = make_uint4(low[0], low[1], low[2], low[3]);
        }
    }
}

// ------------------------------------------------------------ knn select ----
// Exact top-32 per row from hi16 plane + boundary lo16. pos -> col:
// gidx = (pos & ~127) + (pos & 7)*16 + ((pos >> 3) & 15). Full comparator
// = (hi, lo, 2047-gidx) descending == (value desc, low-idx tie-break).
__global__ __launch_bounds__(256) void select_kernel(
    const unsigned short* __restrict__ Kp, const unsigned short* __restrict__ Lp,
    int* __restrict__ idx)
{
    __shared__ unsigned cand[4][256];  // (hi<<12)|pos, 4 KiB
    const int t = threadIdx.x, w = t >> 6, lane = t & 63;
    const int b = blockIdx.x >> 9;
    const int r = (blockIdx.x & 511) * 4 + w;
    const size_t rowbase = ((size_t)(b * 2048 + r)) * 2048;
    int* orow = idx + ((size_t)(b * 2048 + r)) * 32;

    unsigned short kv[32];
#pragma unroll
    for (int q = 0; q < 4; ++q) {
        u16x8 v = *reinterpret_cast<const u16x8*>(Kp + rowbase + lane * 32 + q * 8);
#pragma unroll
        for (int e = 0; e < 8; ++e) kv[q * 8 + e] = v[e];
    }
    unsigned mx = 0;
#pragma unroll
    for (int s = 0; s < 32; ++s) mx = kv[s] > mx ? (unsigned)kv[s] : mx;
    // T = 32nd-largest per-lane max (16-bit ballot radix)
    unsigned T = 0;
#pragma unroll
    for (int bit = 15; bit >= 0; --bit) {
        unsigned c2 = T | (1u << bit);
        if (__popcll(__ballot(mx >= c2)) >= 32) T = c2;
    }
    int c = 0;
#pragma unroll
    for (int s = 0; s < 32; ++s) c += (kv[s] >= T) ? 1 : 0;
    int pfx = c;
#pragma unroll
    for (int d = 1; d < 64; d <<= 1) {
        int o = __shfl_up(pfx, d);
        pfx += (lane >= d) ? o : 0;
    }
    const int total = __shfl(pfx, 63);   // >= 32 always
    int off = pfx - c;

    if (total <= 256) {  // wave-uniform fast path (typical: ~35-60)
#pragma unroll
        for (int s = 0; s < 32; ++s) {
            if (kv[s] >= T) {
                cand[w][off] = ((unsigned)kv[s] << 12) | (unsigned)(lane * 32 + s);
                ++off;
            }
        }
        asm volatile("s_waitcnt lgkmcnt(0)" ::: "memory");
        __builtin_amdgcn_sched_barrier(0);
        bool val[4]; unsigned hi[4], pos_[4];
#pragma unroll
        for (int s2 = 0; s2 < 4; ++s2) {
            int i2 = lane + 64 * s2;
            unsigned e2 = cand[w][i2];
            val[s2] = i2 < total;
            hi[s2] = e2 >> 12;
            pos_[s2] = e2 & 0xFFFu;
        }
        // S = 32nd-largest candidate hi
        unsigned S = 0;
#pragma unroll
        for (int bit = 15; bit >= 0; --bit) {
            unsigned c2 = S | (1u << bit);
            int cnt = 0;
#pragma unroll
            for (int s2 = 0; s2 < 4; ++s2)
                cnt += __popcll(__ballot(val[s2] && hi[s2] >= c2));
            if (cnt >= 32) S = c2;
        }
        bool isin[4], bnd[4];
        int cin = 0;
#pragma unroll
        for (int s2 = 0; s2 < 4; ++s2) {
            isin[s2] = val[s2] && hi[s2] > S;
            bnd[s2]  = val[s2] && hi[s2] == S;
            cin += __popcll(__ballot(isin[s2]));
        }
        const int need = 32 - cin;            // >= 1
        unsigned lo16[4];
#pragma unroll
        for (int s2 = 0; s2 < 4; ++s2)
            lo16[s2] = bnd[s2] ? (unsigned)Lp[rowbase + pos_[s2]] : 0u;
        // L = need-th largest lo16 among boundary
        unsigned L = 0;
#pragma unroll
        for (int bit = 15; bit >= 0; --bit) {
            unsigned c2 = L | (1u << bit);
            int cnt = 0;
#pragma unroll
            for (int s2 = 0; s2 < 4; ++s2)
                cnt += __popcll(__ballot(bnd[s2] && lo16[s2] >= c2));
            if (cnt >= need) L = c2;
        }
        bool in2[4], bnd2[4];
        int a2 = 0;
#pragma unroll
        for (int s2 = 0; s2 < 4; ++s2) {
            in2[s2]  = bnd[s2] && lo16[s2] > L;
            bnd2[s2] = bnd[s2] && lo16[s2] == L;
            a2 += __popcll(__ballot(in2[s2]));
        }
        const int need2 = need - a2;          // >= 1
        unsigned lo11[4]; int gix[4];
#pragma unroll
        for (int s2 = 0; s2 < 4; ++s2) {
            unsigned p = pos_[s2];
            gix[s2] = (int)((p & ~127u) + (p & 7u) * 16u + ((p >> 3) & 15u));
            lo11[s2] = 2047u - (unsigned)gix[s2];
        }
        unsigned L2 = 0;
#pragma unroll
        for (int bit = 10; bit >= 0; --bit) {
            unsigned c2 = L2 | (1u << bit);
            int cnt = 0;
#pragma unroll
            for (int s2 = 0; s2 < 4; ++s2)
                cnt += __popcll(__ballot(bnd2[s2] && lo11[s2] >= c2));
            if (cnt >= need2) L2 = c2;
        }
        bool sel[4]; int nsel = 0;
#pragma unroll
        for (int s2 = 0; s2 < 4; ++s2) {
            sel[s2] = isin[s2] || in2[s2] || (bnd2[s2] && lo11[s2] >= L2);
            nsel += sel[s2] ? 1 : 0;
        }
        int p2 = nsel;
#pragma unroll
        for (int d = 1; d < 64; d <<= 1) {
            int o = __shfl_up(p2, d);
            p2 += (lane >= d) ? o : 0;
        }
        int wo = p2 - nsel;
#pragma unroll
        for (int s2 = 0; s2 < 4; ++s2)
            if (sel[s2]) { orow[wo] = gix[s2]; ++wo; }
    } else {
        // exact fallback (rare): full u32 keys, masked-rescan tournament
        unsigned short lv[32];
#pragma unroll
        for (int q = 0; q < 4; ++q) {
            u16x8 v2 = *reinterpret_cast<const u16x8*>(Lp + rowbase + lane * 32 + q * 8);
#pragma unroll
            for (int e = 0; e < 8; ++e) lv[q * 8 + e] = v2[e];
        }
        unsigned ku[32], lidx[32];
#pragma unroll
        for (int s = 0; s < 32; ++s) {
            ku[s] = ((unsigned)kv[s] << 16) | (unsigned)lv[s];
            unsigned p = (unsigned)(lane * 32 + s);
            unsigned g2 = (p & ~127u) + (p & 7u) * 16u + ((p >> 3) & 15u);
            lidx[s] = 2047u - g2;
        }
        unsigned cons = 0u;
        for (int it = 0; it < 32; ++it) {
            unsigned b2 = 0u, l2 = 0u;
#pragma unroll
            for (int s = 0; s < 32; ++s) {
                bool ok = !((cons >> s) & 1u) &&
                          ((ku[s] > b2) || (ku[s] == b2 && lidx[s] > l2));
                b2 = ok ? ku[s] : b2;
                l2 = ok ? lidx[s] : l2;
            }
            unsigned wsv = b2, wlo = l2;
#pragma unroll
            for (int d = 1; d < 64; d <<= 1) {
                unsigned osv = __shfl_xor(wsv, d);
                unsigned olo = __shfl_xor(wlo, d);
                bool take = (osv > wsv) || (osv == wsv && olo > wlo);
                wsv = take ? osv : wsv;
                wlo = take ? olo : wlo;
            }
            int g2 = 2047 - (int)wlo;
            unsigned p = (unsigned)((g2 & ~127) + (g2 & 15) * 8 + ((g2 >> 4) & 7));
            if (lane == (int)(p >> 5)) cons |= 1u << (p & 31u);
            if (lane == 0) orow[it] = g2;
        }
    }
}

// ---------------------------------------------------------------- attn ------
// 4 points/block, 1 wave/point. Energies inline during K gather; V in LDS.
// R18 change vs R16: es last dim 32 -> 33 (kills the serial-softmax 32-way
// bank conflict; indexing/semantics unchanged).
__global__ __launch_bounds__(256) void attn_kernel(
    const float* __restrict__ x, const float* __restrict__ Qp,
    const float* __restrict__ KT, const float* __restrict__ VT,
    const int* __restrict__ idx, float* __restrict__ A1)
{
    __shared__ float Vn[4][32][66];
    __shared__ float qs[4][64], xq[4][64], vsf[4][64];
    __shared__ float es[4][8][33];
    const int t = threadIdx.x, w = t >> 6, lane = t & 63;
    const int b = blockIdx.x >> 9;
    const int n = (blockIdx.x & 511) * 4 + w;
    const size_t prow = (size_t)(b * 2048 + n);
    const size_t pbase = prow * 64;

    qs[w][lane]  = Qp[pbase + lane];
    xq[w][lane]  = x[((size_t)b * 64 + lane) * 2048 + n];
    vsf[w][lane] = VT[pbase + lane];
    asm volatile("s_waitcnt lgkmcnt(0)" ::: "memory");
    __builtin_amdgcn_sched_barrier(0);
    {
        const int j = lane >> 1, half = lane & 1, c0 = half * 32;
        const int nbi = idx[prow * 32 + j] & 2047;
        const float* kr = KT + ((size_t)(b * 2048 + nbi)) * 64 + c0;
        const float* vr = VT + ((size_t)(b * 2048 + nbi)) * 64 + c0;
        float eh[4] = {0.f, 0.f, 0.f, 0.f};
#pragma unroll
        for (int q = 0; q < 8; ++q) {
            float4 kq = *reinterpret_cast<const float4*>(kr + q * 4);
            float4 qv = *reinterpret_cast<const float4*>(&qs[w][c0 + q * 4]);
            const int hh = q >> 1;
            eh[hh] += qv.x * kq.x;
            eh[hh] += qv.y * kq.y;
            eh[hh] += qv.z * kq.z;
            eh[hh] += qv.w * kq.w;
            *reinterpret_cast<float4*>(&Vn[w][j][c0 + q * 4]) =
                *reinterpret_cast<const float4*>(vr + q * 4);
        }
#pragma unroll
        for (int hh = 0; hh < 4; ++hh) es[w][half * 4 + hh][j] = eh[hh];
    }
    __syncthreads();
    if (t < 32) {
        int w2 = t >> 3, h = t & 7;
        float mxv = -INFINITY;
#pragma unroll
        for (int j = 0; j < 32; ++j) mxv = fmaxf(mxv, es[w2][h][j]);
        float pv[32], s = 0.f;
#pragma unroll
        for (int j = 0; j < 32; ++j) { pv[j] = __expf(es[w2][h][j] - mxv); s += pv[j]; }
        float inv = 1.f / s;
#pragma unroll
        for (int j = 0; j < 32; ++j) es[w2][h][j] = pv[j] * inv;
    }
    __syncthreads();
    {
        const int h = lane >> 3;
        float acc = 0.f;
#pragma unroll
        for (int j = 0; j < 32; ++j) acc += es[w][h][j] * Vn[w][j][lane];
        A1[pbase + lane] = acc - vsf[w][lane] + xq[w][lane];
    }
}

// ------------------------------------------------------------- BN stats -----
__global__ __launch_bounds__(256) void bn_partial_kernel(
    const float* __restrict__ Y, float* __restrict__ psum, float* __restrict__ psq)
{
    __shared__ float rs[4][64], rq[4][64];
    const int t = threadIdx.x;
    const int c = t & 63, pg = t >> 6;
    const int b = blockIdx.x >> 5;
    const int n0 = (blockIdx.x & 31) * 64;
    float s = 0.f, q = 0.f;
    for (int k = 0; k < 16; ++k) {
        float v = Y[((size_t)(b * 2048 + n0 + pg * 16 + k)) * 64 + c];
        s += v; q += v * v;
    }
    rs[pg][c] = s; rq[pg][c] = q;
    __syncthreads();
    if (t < 64) {
        psum[blockIdx.x * 64 + t] = rs[0][t] + rs[1][t] + rs[2][t] + rs[3][t];
        psq[blockIdx.x * 64 + t]  = rq[0][t] + rq[1][t] + rq[2][t] + rq[3][t];
    }
}

__global__ void bn_final_kernel(
    const float* __restrict__ psum, const float* __restrict__ psq,
    const float* __restrict__ gamma, const float* __restrict__ beta,
    float* __restrict__ sc, float* __restrict__ sh)
{
    int c = threadIdx.x;  // 64 threads
    float s = 0.f, q = 0.f;
    for (int i = 0; i < 256; ++i) { s += psum[i * 64 + c]; q += psq[i * 64 + c]; }
    float mean = s * (1.f / 16384.f);
    float var = q * (1.f / 16384.f) - mean * mean;
    float g = gamma[c] * rsqrtf(var + 1e-5f);
    sc[c] = g;
    sh[c] = beta[c] - mean * g;
}

// ------------------------------------------------------------ FFN fused -----
__global__ __launch_bounds__(256) void ffn_kernel(
    const float* __restrict__ A1, const float* __restrict__ W1,
    const float* __restrict__ W2, const float* __restrict__ s1,
    const float* __restrict__ t1, float* __restrict__ P2)
{
    __shared__ float W1s[8192];
    __shared__ float W2s[8192];
    __shared__ float xs[64][65];
    __shared__ float hs[64][129];
    __shared__ float sts[64], stt[64];
    const int t = threadIdx.x;
    const int b = blockIdx.x >> 5;
    const int n0 = (blockIdx.x & 31) * 64;
    if (t < 64) { sts[t] = s1[t]; stt[t] = t1[t]; }
    for (int i = 0; i < 32; ++i) {
        int e = t + 256 * i;
        W1s[e] = W1[e];
        W2s[e] = W2[e];
    }
    __syncthreads();
    for (int i = 0; i < 16; ++i) {
        int e = t + 256 * i, p = e >> 6, c = e & 63;
        xs[p][c] = A1[((size_t)(b * 2048 + n0 + p)) * 64 + c] * sts[c] + stt[c];
    }
    __syncthreads();
    const int p = t & 63, g = t >> 6;
    {
        float xv[64];
#pragma unroll
        for (int c = 0; c < 64; ++c) xv[c] = xs[p][c];
        for (int u = 0; u < 32; ++u) {
            int j = g * 32 + u;
            float acc = 0.f;
#pragma unroll
            for (int c = 0; c < 64; ++c) acc += W1s[j * 64 + c] * xv[c];
            hs[p][j] = (acc > 0.f) ? acc : 0.2f * acc;  // LeakyReLU 0.2
        }
    }
    __syncthreads();
    {
        float hv[128];
#pragma unroll
        for (int j = 0; j < 128; ++j) hv[j] = hs[p][j];
        const size_t pbase = ((size_t)(b * 2048 + n0 + p)) * 64 + g * 16;
        float o4[16];
#pragma unroll
        for (int oi = 0; oi < 16; ++oi) {
            int o = g * 16 + oi;
            float a = xs[p][o];  // residual x1
#pragma unroll
            for (int j = 0; j < 128; ++j) a += W2s[o * 128 + j] * hv[j];
            o4[oi] = a;
        }
#pragma unroll
        for (int q = 0; q < 4; ++q)
            *reinterpret_cast<float4*>(P2 + pbase + q * 4) =
                make_float4(o4[q * 4], o4[q * 4 + 1], o4[q * 4 + 2], o4[q * 4 + 3]);
    }
}

// ---------------------------------------------------------------- final -----
__global__ __launch_bounds__(256) void final_kernel(
    const float* __restrict__ P2, const float* __restrict__ s2,
    const float* __restrict__ t2, float* __restrict__ out)
{
    __shared__ float ts[64][65];
    __shared__ float sts[64], stt[64];
    const int t = threadIdx.x;
    const int b = blockIdx.x >> 5;
    const int n0 = (blockIdx.x & 31) * 64;
    if (t < 64) { sts[t] = s2[t]; stt[t] = t2[t]; }
    __syncthreads();
    for (int i = 0; i < 16; ++i) {
        int e = t + 256 * i, p = e >> 6, c = e & 63;
        ts[p][c] = P2[((size_t)(b * 2048 + n0 + p)) * 64 + c] * sts[c] + stt[c];
    }
    __syncthreads();
    const int c = t >> 2, p0 = (t & 3) * 16;
    float* dst = out + ((size_t)(b * 64 + c)) * 2048 + n0 + p0;
#pragma unroll
    for (int q = 0; q < 4; ++q)
        *reinterpret_cast<float4*>(dst + q * 4) =
            make_float4(ts[p0 + q * 4 + 0][c], ts[p0 + q * 4 + 1][c],
                        ts[p0 + q * 4 + 2][c], ts[p0 + q * 4 + 3][c]);
}

// ------------------------------------------------------- safe fallback ------
__global__ __launch_bounds__(256) void zero_kernel(float* __restrict__ out)
{
    reinterpret_cast<float4*>(out)[blockIdx.x * 256 + threadIdx.x] =
        make_float4(0.f, 0.f, 0.f, 0.f);  // 1024*256*16B = 4 MiB
}

// ---------------------------------------------------------------- launch ----
extern "C" void kernel_launch(void* const* d_in, const int* in_sizes, int n_in,
                              void* d_out, int out_size, void* d_ws, size_t ws_size,
                              hipStream_t stream)
{
    const float* x  = (const float*)d_in[0];
    const float* Wq = (const float*)d_in[1];
    const float* Wk = (const float*)d_in[2];
    const float* Wv = (const float*)d_in[3];
    const float* W1 = (const float*)d_in[4];
    const float* W2 = (const float*)d_in[5];
    const float* g1 = (const float*)d_in[6];
    const float* b1 = (const float*)d_in[7];
    const float* g2 = (const float*)d_in[8];
    const float* b2 = (const float*)d_in[9];
    float* out = (float*)d_out;
    (void)in_sizes; (void)n_in; (void)out_size;

    char* ws = (char*)d_ws;
    const size_t off_xx  = 0;                   // 64 KiB
    const size_t off_KT  = 65536;               // 4 MiB fp32 (P2 overlays after attn)
    const size_t off_VT  = off_KT  + 4194304;   // 4 MiB
    const size_t off_idx = off_VT  + 4194304;   // 2 MiB int (xh plane before select)
    const size_t off_A1  = off_idx + 2097152;   // 4 MiB fp32 (xm+xl planes before attn)
    const size_t off_s1  = off_A1  + 4194304;
    const size_t off_t1  = off_s1 + 256;
    const size_t off_s2  = off_t1 + 256;
    const size_t off_t2  = off_s2 + 256;
    const size_t off_Dp  = 14815232;            // key planes region, 4 KiB aligned
    const size_t KP_SZ   = (size_t)8 * 2048 * 2048 * 2;  // 64 MiB
    const size_t REQ_FAST = off_Dp + 2 * KP_SZ; // ~142.2 MiB

    if (ws_size < REQ_FAST) {  // constant per capture: safe fail
        zero_kernel<<<1024, 256, 0, stream>>>(out);
        return;
    }

    float* xx = (float*)(ws + off_xx);
    float* KT = (float*)(ws + off_KT);
    float* VT = (float*)(ws + off_VT);
    int* idx  = (int*)(ws + off_idx);
    float* A1 = (float*)(ws + off_A1);
    float* P2 = KT;  // KT dead after attn
    short* xh = (short*)(ws + off_idx);
    short* xm = (short*)(ws + off_A1);
    short* xl = (short*)(ws + off_A1 + 2097152);
    float* s1 = (float*)(ws + off_s1); float* t1 = (float*)(ws + off_t1);
    float* s2 = (float*)(ws + off_s2); float* t2 = (float*)(ws + off_t2);
    unsigned short* Kp = (unsigned short*)(ws + off_Dp);
    unsigned short* Lp = (unsigned short*)(ws + off_Dp + KP_SZ);
    float* Qp = (float*)(ws + off_Dp);   // overlays Kp (dead after select)
    float* ps1 = (float*)(ws + off_Dp);  // BN partials overlay (Qp dead post-attn)
    float* pq1 = ps1 + 16384;
    float* ps2 = ps1 + 32768;
    float* pq2 = ps1 + 49152;

    prep_kernel<<<512, 256, 0, stream>>>(x, Wk, Wv, xx, KT, VT, xh, xm, xl);
    gemm_kernel<<<2048, 256, 0, stream>>>(xh, xm, xl, xx, Kp, Lp);
    select_kernel<<<4096, 256, 0, stream>>>(Kp, Lp, idx);
    qproj_kernel<<<512, 256, 0, stream>>>(x, Wq, Qp);
    attn_kernel<<<4096, 256, 0, stream>>>(x, Qp, KT, VT, idx, A1);
    bn_partial_kernel<<<256, 256, 0, stream>>>(A1, ps1, pq1);
    bn_final_kernel<<<1, 64, 0, stream>>>(ps1, pq1, g1, b1, s1, t1);
    ffn_kernel<<<256, 256, 0, stream>>>(A1, W1, W2, s1, t1, P2);
    bn_partial_kernel<<<256, 256, 0, stream>>>(P2, ps2, pq2);
    bn_final_kernel<<<1, 64, 0, stream>>>(ps2, pq2, g2, b2, s2, t2);
    final_kernel<<<256, 256, 0, stream>>>(P2, s2, t2, out);
}

// Round 11
// 260.724 us; speedup vs baseline: 1.0537x; 1.0537x over previous
//
#include <hip/hip_runtime.h>

// B=8, C=64, N=2048, K=32, H=8, d=8. Inputs FLOAT32; output FLOAT32.
// R19 (vs R18, attn ONLY changed): V is no longer staged in LDS — PV reads
// V[nbi_j*64 + lane] straight from global (one coalesced 256B read per
// neighbor; VT is 4MB = L2-resident; 32 independent loads pipeline).
// LDS 41.4KB -> ~7.9KB => occupancy 3 -> 8 blocks/CU (R18 counters: attn
// latency-bound, VALUBusy 9%, occ 27%). Neighbor idxs kept in tiny LDS.
// All summation orders bit-identical to R18 (PV j-ascending, same values);
// serial softmax + es[33] pad kept. Everything else byte-identical to R18.

#define NN 2048

typedef __attribute__((ext_vector_type(8))) short bf16x8;
typedef __attribute__((ext_vector_type(8))) unsigned short u16x8;
typedef __attribute__((ext_vector_type(4))) float f32x4;

// Exact 3-way bf16 split of an f32 value (hi+mid+lo == x exactly).
__device__ inline void bsplit(float x, short& h, short& m, short& l)
{
    unsigned u  = __float_as_uint(x);
    unsigned hb = (u + 0x7FFFu + ((u >> 16) & 1u)) >> 16;
    float hf = __uint_as_float(hb << 16);
    float r1 = x - hf;                       // exact (Sterbenz)
    unsigned u1 = __float_as_uint(r1);
    unsigned mb = (u1 + 0x7FFFu + ((u1 >> 16) & 1u)) >> 16;
    float mf = __uint_as_float(mb << 16);
    float r2 = r1 - mf;                      // exact; <= 8 significant bits
    unsigned u2 = __float_as_uint(r2);
    unsigned lb = (u2 + 0x7FFFu + ((u2 >> 16) & 1u)) >> 16;
    h = (short)hb; m = (short)mb; l = (short)lb;
}

// ---------------------------------------------------------------- prep ------
__global__ __launch_bounds__(256) void prep_kernel(
    const float* __restrict__ x, const float* __restrict__ Wk,
    const float* __restrict__ Wv, float* __restrict__ xx,
    float* __restrict__ KT, float* __restrict__ VT,
    short* __restrict__ xh, short* __restrict__ xm, short* __restrict__ xl)
{
    __shared__ float xs[64][33];
    __shared__ float wks[4096], wvs[4096];
    const int t = threadIdx.x;
    const int b = blockIdx.x >> 6;
    const int n0 = (blockIdx.x & 63) * 32;
    for (int i = 0; i < 16; ++i) {
        int e = t + 256 * i;
        wks[e] = Wk[e];
        wvs[e] = Wv[e];
    }
    for (int i = 0; i < 8; ++i) {
        int e = t + 256 * i;
        xs[e >> 5][e & 31] = x[((size_t)b * 64 + (e >> 5)) * 2048 + n0 + (e & 31)];
    }
    __syncthreads();
    if (t < 32) {
        float s = 0.f;
#pragma unroll
        for (int c = 0; c < 64; ++c) { float v = xs[c][t]; s += v * v; }
        xx[b * 2048 + n0 + t] = s;
    }
    const int p = t & 31, g = t >> 5;
    {   // split planes: thread (p,g) -> channels [g*8, g*8+8) of point p
        u16x8 vh, vm, vl;
#pragma unroll
        for (int ci = 0; ci < 8; ++ci) {
            short h, m, l;
            bsplit(xs[g * 8 + ci][p], h, m, l);
            vh[ci] = (unsigned short)h; vm[ci] = (unsigned short)m; vl[ci] = (unsigned short)l;
        }
        size_t base = ((size_t)(b * 2048 + n0 + p)) * 64 + g * 8;
        *reinterpret_cast<u16x8*>(xh + base) = vh;
        *reinterpret_cast<u16x8*>(xm + base) = vm;
        *reinterpret_cast<u16x8*>(xl + base) = vl;
    }
    {   // K/V projections: 8 output channels per thread
        float xv[64];
#pragma unroll
        for (int c = 0; c < 64; ++c) xv[c] = xs[c][p];
        size_t base = ((size_t)(b * 2048 + n0 + p)) * 64 + g * 8;
        float ok[8], ov[8];
#pragma unroll
        for (int oi = 0; oi < 8; ++oi) {
            int o = g * 8 + oi;
            float ak = 0.f, av = 0.f;
#pragma unroll
            for (int c = 0; c < 64; ++c) {
                float xc = xv[c];
                ak += wks[o * 64 + c] * xc;
                av += wvs[o * 64 + c] * xc;
            }
            ok[oi] = ak; ov[oi] = av;
        }
        *reinterpret_cast<float4*>(KT + base)     = make_float4(ok[0], ok[1], ok[2], ok[3]);
        *reinterpret_cast<float4*>(KT + base + 4) = make_float4(ok[4], ok[5], ok[6], ok[7]);
        *reinterpret_cast<float4*>(VT + base)     = make_float4(ov[0], ov[1], ov[2], ov[3]);
        *reinterpret_cast<float4*>(VT + base + 4) = make_float4(ov[4], ov[5], ov[6], ov[7]);
    }
}

// ---------------------------------------------------------------- qproj -----
__global__ __launch_bounds__(256) void qproj_kernel(
    const float* __restrict__ x, const float* __restrict__ Wq,
    float* __restrict__ Qp)
{
    __shared__ float xs[64][33];
    __shared__ float wqs[4096];
    const int t = threadIdx.x;
    const int b = blockIdx.x >> 6;
    const int n0 = (blockIdx.x & 63) * 32;
    for (int i = 0; i < 16; ++i) { int e = t + 256 * i; wqs[e] = Wq[e]; }
    for (int i = 0; i < 8; ++i) {
        int e = t + 256 * i;
        xs[e >> 5][e & 31] = x[((size_t)b * 64 + (e >> 5)) * 2048 + n0 + (e & 31)];
    }
    __syncthreads();
    const int p = t & 31, g = t >> 5;
    float xv[64];
#pragma unroll
    for (int c = 0; c < 64; ++c) xv[c] = xs[c][p];
    size_t base = ((size_t)(b * 2048 + n0 + p)) * 64 + g * 8;
    float oq[8];
#pragma unroll
    for (int oi = 0; oi < 8; ++oi) {
        int o = g * 8 + oi;
        float a = 0.f;
#pragma unroll
        for (int c = 0; c < 64; ++c) a += wqs[o * 64 + c] * xv[c];
        oq[oi] = a * 0.35355339059327379f;
    }
    *reinterpret_cast<float4*>(Qp + base)     = make_float4(oq[0], oq[1], oq[2], oq[3]);
    *reinterpret_cast<float4*>(Qp + base + 4) = make_float4(oq[4], oq[5], oq[6], oq[7]);
}

// ------------------------------------------------------------- knn gemm -----
// D'[b][n][m] = (2*G[n][m] - xx[n]) - xx[m]; sortable u32 key stored as
// hi16 -> Kp, lo16 -> Lp at pos = c0 + rl*8 + cb (col = c0 + cb*16 + rl).
// MFMA order identical to R12: lh,hl,mm,mh,hm,hh.
__device__ inline void mm6(f32x4& a, bf16x8 Ah, bf16x8 Am, bf16x8 Al,
                           bf16x8 Bh, bf16x8 Bm, bf16x8 Bl)
{
    a = __builtin_amdgcn_mfma_f32_16x16x32_bf16(Al, Bh, a, 0, 0, 0);
    a = __builtin_amdgcn_mfma_f32_16x16x32_bf16(Ah, Bl, a, 0, 0, 0);
    a = __builtin_amdgcn_mfma_f32_16x16x32_bf16(Am, Bm, a, 0, 0, 0);
    a = __builtin_amdgcn_mfma_f32_16x16x32_bf16(Am, Bh, a, 0, 0, 0);
    a = __builtin_amdgcn_mfma_f32_16x16x32_bf16(Ah, Bm, a, 0, 0, 0);
    a = __builtin_amdgcn_mfma_f32_16x16x32_bf16(Ah, Bh, a, 0, 0, 0);
}

__global__ __launch_bounds__(256) void gemm_kernel(
    const short* __restrict__ xh, const short* __restrict__ xm,
    const short* __restrict__ xl, const float* __restrict__ xx,
    unsigned short* __restrict__ Kp, unsigned short* __restrict__ Lp)
{
    __shared__ short BhL[8192], BmL[8192], BlL[8192];  // 48 KiB
    const int t = threadIdx.x;
    const int lane = t & 63;
    const int w = t >> 6;
    const int b = blockIdx.x >> 8;
    const int tile = blockIdx.x & 255;
    const int r0 = (tile >> 4) * 128 + w * 32;
    const int c0 = (tile & 15) * 128;
    const int rl = lane & 15;
    const int g = lane >> 4;
    const int kg = g * 8;

    const size_t boff = (size_t)b * 2048 * 64;
    const short* XH = xh + boff;
    const short* XM = xm + boff;
    const short* XL = xl + boff;

    bf16x8 aH[2][2], aM[2][2], aL[2][2];
#pragma unroll
    for (int s = 0; s < 2; ++s)
#pragma unroll
        for (int rb = 0; rb < 2; ++rb) {
            const size_t ab = (size_t)(r0 + rb * 16 + rl) * 64 + s * 32 + kg;
            aH[s][rb] = *reinterpret_cast<const bf16x8*>(XH + ab);
            aM[s][rb] = *reinterpret_cast<const bf16x8*>(XM + ab);
            aL[s][rb] = *reinterpret_cast<const bf16x8*>(XL + ab);
        }

    {   // stage B panel; 16B chunk swizzle j ^= col&7
        const short* sH = XH + (size_t)c0 * 64;
        const short* sM = XM + (size_t)c0 * 64;
        const short* sL = XL + (size_t)c0 * 64;
#pragma unroll
        for (int i = 0; i < 4; ++i) {
            int ci = t + 256 * i;
            int col = ci >> 3, j = ci & 7;
            int d = col * 64 + ((j ^ (col & 7)) << 3);
            *reinterpret_cast<u16x8*>(BhL + d) = *reinterpret_cast<const u16x8*>(sH + ci * 8);
            *reinterpret_cast<u16x8*>(BmL + d) = *reinterpret_cast<const u16x8*>(sM + ci * 8);
            *reinterpret_cast<u16x8*>(BlL + d) = *reinterpret_cast<const u16x8*>(sL + ci * 8);
        }
    }
    __syncthreads();

    f32x4 acc[2][8];
#pragma unroll
    for (int rb = 0; rb < 2; ++rb)
#pragma unroll
        for (int cb = 0; cb < 8; ++cb)
            acc[rb][cb] = (f32x4){0.f, 0.f, 0.f, 0.f};

#pragma unroll
    for (int cb = 0; cb < 8; ++cb) {
        __builtin_amdgcn_sched_barrier(0);
        const int cl = cb * 16 + rl;
#pragma unroll
        for (int s = 0; s < 2; ++s) {
            const int d = cl * 64 + (((s * 4 + g) ^ (cl & 7)) << 3);
            bf16x8 Bh = *reinterpret_cast<const bf16x8*>(BhL + d);
            bf16x8 Bm = *reinterpret_cast<const bf16x8*>(BmL + d);
            bf16x8 Bl = *reinterpret_cast<const bf16x8*>(BlL + d);
            mm6(acc[0][cb], aH[s][0], aM[s][0], aL[s][0], Bh, Bm, Bl);
            mm6(acc[1][cb], aH[s][1], aM[s][1], aL[s][1], Bh, Bm, Bl);
        }
    }
    __builtin_amdgcn_sched_barrier(0);

    // epilogue: C/D layout col=lane&15, row=(lane>>4)*4+reg; store key planes
    const float* xxb = xx + b * 2048;
    const int rg = g * 4;
#pragma unroll
    for (int rb = 0; rb < 2; ++rb) {
#pragma unroll
        for (int e = 0; e < 4; ++e) {
            const int row = r0 + rb * 16 + rg + e;
            const float xn = xxb[row];
            unsigned hiw[4], low[4];
#pragma unroll
            for (int cp = 0; cp < 4; ++cp) {
                unsigned su[2];
#pragma unroll
                for (int h2 = 0; h2 < 2; ++h2) {
                    const int cb = cp * 2 + h2;
                    float v = 2.f * acc[rb][cb][e] - xn;   // (2G - xx_n)
                    v = v - xxb[c0 + cb * 16 + rl];        // ... - xx_m
                    unsigned u = __float_as_uint(v);
                    su[h2] = u ^ (unsigned)(((int)u >> 31) | 0x80000000);
                }
                hiw[cp] = (su[0] >> 16) | (su[1] & 0xFFFF0000u);
                low[cp] = (su[0] & 0xFFFFu) | (su[1] << 16);
            }
            const size_t base = ((size_t)(b * 2048 + row)) * 2048 + c0 + rl * 8;
            *reinterpret_cast<uint4*>(Kp + base) = make_uint4(hiw[0], hiw[1], hiw[2], hiw[3]);
            *reinterpret_cast<uint4*>(Lp + base) = make_uint4(low[0], low[1], low[2], low[3]);
        }
    }
}

// ------------------------------------------------------------ knn select ----
// Exact top-32 per row from hi16 plane + boundary lo16. pos -> col:
// gidx = (pos & ~127) + (pos & 7)*16 + ((pos >> 3) & 15). Full comparator
// = (hi, lo, 2047-gidx) descending == (value desc, low-idx tie-break).
__global__ __launch_bounds__(256) void select_kernel(
    const unsigned short* __restrict__ Kp, const unsigned short* __restrict__ Lp,
    int* __restrict__ idx)
{
    __shared__ unsigned cand[4][256];  // (hi<<12)|pos, 4 KiB
    const int t = threadIdx.x, w = t >> 6, lane = t & 63;
    const int b = blockIdx.x >> 9;
    const int r = (blockIdx.x & 511) * 4 + w;
    const size_t rowbase = ((size_t)(b * 2048 + r)) * 2048;
    int* orow = idx + ((size_t)(b * 2048 + r)) * 32;

    unsigned short kv[32];
#pragma unroll
    for (int q = 0; q < 4; ++q) {
        u16x8 v = *reinterpret_cast<const u16x8*>(Kp + rowbase + lane * 32 + q * 8);
#pragma unroll
        for (int e = 0; e < 8; ++e) kv[q * 8 + e] = v[e];
    }
    unsigned mx = 0;
#pragma unroll
    for (int s = 0; s < 32; ++s) mx = kv[s] > mx ? (unsigned)kv[s] : mx;
    // T = 32nd-largest per-lane max (16-bit ballot radix)
    unsigned T = 0;
#pragma unroll
    for (int bit = 15; bit >= 0; --bit) {
        unsigned c2 = T | (1u << bit);
        if (__popcll(__ballot(mx >= c2)) >= 32) T = c2;
    }
    int c = 0;
#pragma unroll
    for (int s = 0; s < 32; ++s) c += (kv[s] >= T) ? 1 : 0;
    int pfx = c;
#pragma unroll
    for (int d = 1; d < 64; d <<= 1) {
        int o = __shfl_up(pfx, d);
        pfx += (lane >= d) ? o : 0;
    }
    const int total = __shfl(pfx, 63);   // >= 32 always
    int off = pfx - c;

    if (total <= 256) {  // wave-uniform fast path (typical: ~35-60)
#pragma unroll
        for (int s = 0; s < 32; ++s) {
            if (kv[s] >= T) {
                cand[w][off] = ((unsigned)kv[s] << 12) | (unsigned)(lane * 32 + s);
                ++off;
            }
        }
        asm volatile("s_waitcnt lgkmcnt(0)" ::: "memory");
        __builtin_amdgcn_sched_barrier(0);
        bool val[4]; unsigned hi[4], pos_[4];
#pragma unroll
        for (int s2 = 0; s2 < 4; ++s2) {
            int i2 = lane + 64 * s2;
            unsigned e2 = cand[w][i2];
            val[s2] = i2 < total;
            hi[s2] = e2 >> 12;
            pos_[s2] = e2 & 0xFFFu;
        }
        // S = 32nd-largest candidate hi
        unsigned S = 0;
#pragma unroll
        for (int bit = 15; bit >= 0; --bit) {
            unsigned c2 = S | (1u << bit);
            int cnt = 0;
#pragma unroll
            for (int s2 = 0; s2 < 4; ++s2)
                cnt += __popcll(__ballot(val[s2] && hi[s2] >= c2));
            if (cnt >= 32) S = c2;
        }
        bool isin[4], bnd[4];
        int cin = 0;
#pragma unroll
        for (int s2 = 0; s2 < 4; ++s2) {
            isin[s2] = val[s2] && hi[s2] > S;
            bnd[s2]  = val[s2] && hi[s2] == S;
            cin += __popcll(__ballot(isin[s2]));
        }
        const int need = 32 - cin;            // >= 1
        unsigned lo16[4];
#pragma unroll
        for (int s2 = 0; s2 < 4; ++s2)
            lo16[s2] = bnd[s2] ? (unsigned)Lp[rowbase + pos_[s2]] : 0u;
        // L = need-th largest lo16 among boundary
        unsigned L = 0;
#pragma unroll
        for (int bit = 15; bit >= 0; --bit) {
            unsigned c2 = L | (1u << bit);
            int cnt = 0;
#pragma unroll
            for (int s2 = 0; s2 < 4; ++s2)
                cnt += __popcll(__ballot(bnd[s2] && lo16[s2] >= c2));
            if (cnt >= need) L = c2;
        }
        bool in2[4], bnd2[4];
        int a2 = 0;
#pragma unroll
        for (int s2 = 0; s2 < 4; ++s2) {
            in2[s2]  = bnd[s2] && lo16[s2] > L;
            bnd2[s2] = bnd[s2] && lo16[s2] == L;
            a2 += __popcll(__ballot(in2[s2]));
        }
        const int need2 = need - a2;          // >= 1
        unsigned lo11[4]; int gix[4];
#pragma unroll
        for (int s2 = 0; s2 < 4; ++s2) {
            unsigned p = pos_[s2];
            gix[s2] = (int)((p & ~127u) + (p & 7u) * 16u + ((p >> 3) & 15u));
            lo11[s2] = 2047u - (unsigned)gix[s2];
        }
        unsigned L2 = 0;
#pragma unroll
        for (int bit = 10; bit >= 0; --bit) {
            unsigned c2 = L2 | (1u << bit);
            int cnt = 0;
#pragma unroll
            for (int s2 = 0; s2 < 4; ++s2)
                cnt += __popcll(__ballot(bnd2[s2] && lo11[s2] >= c2));
            if (cnt >= need2) L2 = c2;
        }
        bool sel[4]; int nsel = 0;
#pragma unroll
        for (int s2 = 0; s2 < 4; ++s2) {
            sel[s2] = isin[s2] || in2[s2] || (bnd2[s2] && lo11[s2] >= L2);
            nsel += sel[s2] ? 1 : 0;
        }
        int p2 = nsel;
#pragma unroll
        for (int d = 1; d < 64; d <<= 1) {
            int o = __shfl_up(p2, d);
            p2 += (lane >= d) ? o : 0;
        }
        int wo = p2 - nsel;
#pragma unroll
        for (int s2 = 0; s2 < 4; ++s2)
            if (sel[s2]) { orow[wo] = gix[s2]; ++wo; }
    } else {
        // exact fallback (rare): full u32 keys, masked-rescan tournament
        unsigned short lv[32];
#pragma unroll
        for (int q = 0; q < 4; ++q) {
            u16x8 v2 = *reinterpret_cast<const u16x8*>(Lp + rowbase + lane * 32 + q * 8);
#pragma unroll
            for (int e = 0; e < 8; ++e) lv[q * 8 + e] = v2[e];
        }
        unsigned ku[32], lidx[32];
#pragma unroll
        for (int s = 0; s < 32; ++s) {
            ku[s] = ((unsigned)kv[s] << 16) | (unsigned)lv[s];
            unsigned p = (unsigned)(lane * 32 + s);
            unsigned g2 = (p & ~127u) + (p & 7u) * 16u + ((p >> 3) & 15u);
            lidx[s] = 2047u - g2;
        }
        unsigned cons = 0u;
        for (int it = 0; it < 32; ++it) {
            unsigned b2 = 0u, l2 = 0u;
#pragma unroll
            for (int s = 0; s < 32; ++s) {
                bool ok = !((cons >> s) & 1u) &&
                          ((ku[s] > b2) || (ku[s] == b2 && lidx[s] > l2));
                b2 = ok ? ku[s] : b2;
                l2 = ok ? lidx[s] : l2;
            }
            unsigned wsv = b2, wlo = l2;
#pragma unroll
            for (int d = 1; d < 64; d <<= 1) {
                unsigned osv = __shfl_xor(wsv, d);
                unsigned olo = __shfl_xor(wlo, d);
                bool take = (osv > wsv) || (osv == wsv && olo > wlo);
                wsv = take ? osv : wsv;
                wlo = take ? olo : wlo;
            }
            int g2 = 2047 - (int)wlo;
            unsigned p = (unsigned)((g2 & ~127) + (g2 & 15) * 8 + ((g2 >> 4) & 7));
            if (lane == (int)(p >> 5)) cons |= 1u << (p & 31u);
            if (lane == 0) orow[it] = g2;
        }
    }
}

// ---------------------------------------------------------------- attn ------
// 4 points/block, 1 wave/point. Energies inline during K gather (K read
// 128B per lane-pair); V NOT staged — PV reads V[nbi_j*64 + lane] straight
// from global (coalesced 256B per neighbor, L2-resident, 32 independent
// loads). LDS ~7.9KB -> 8 blocks/CU. Sum orders bit-identical to R18.
__global__ __launch_bounds__(256) void attn_kernel(
    const float* __restrict__ x, const float* __restrict__ Qp,
    const float* __restrict__ KT, const float* __restrict__ VT,
    const int* __restrict__ idx, float* __restrict__ A1)
{
    __shared__ float qs[4][64], xq[4][64], vsf[4][64];
    __shared__ float es[4][8][33];
    __shared__ int idxs[4][32];
    const int t = threadIdx.x, w = t >> 6, lane = t & 63;
    const int b = blockIdx.x >> 9;
    const int n = (blockIdx.x & 511) * 4 + w;
    const size_t prow = (size_t)(b * 2048 + n);
    const size_t pbase = prow * 64;

    qs[w][lane]  = Qp[pbase + lane];
    xq[w][lane]  = x[((size_t)b * 64 + lane) * 2048 + n];
    vsf[w][lane] = VT[pbase + lane];
    if (lane < 32) idxs[w][lane] = idx[prow * 32 + lane] & 2047;  // clamp
    __syncthreads();
    {   // energies: lane -> (j = lane>>1, half = lane&1)
        const int j = lane >> 1, half = lane & 1, c0 = half * 32;
        const int nbi = idxs[w][j];
        const float* kr = KT + ((size_t)(b * 2048 + nbi)) * 64 + c0;
        float eh[4] = {0.f, 0.f, 0.f, 0.f};
#pragma unroll
        for (int q = 0; q < 8; ++q) {
            float4 kq = *reinterpret_cast<const float4*>(kr + q * 4);
            float4 qv = *reinterpret_cast<const float4*>(&qs[w][c0 + q * 4]);
            const int hh = q >> 1;
            eh[hh] += qv.x * kq.x;   // d ascending: matches prior sum order
            eh[hh] += qv.y * kq.y;
            eh[hh] += qv.z * kq.z;
            eh[hh] += qv.w * kq.w;
        }
#pragma unroll
        for (int hh = 0; hh < 4; ++hh) es[w][half * 4 + hh][j] = eh[hh];
    }
    __syncthreads();
    if (t < 32) {  // serial per-head softmax (unchanged semantics)
        int w2 = t >> 3, h = t & 7;
        float mxv = -INFINITY;
#pragma unroll
        for (int j = 0; j < 32; ++j) mxv = fmaxf(mxv, es[w2][h][j]);
        float pv[32], s = 0.f;
#pragma unroll
        for (int j = 0; j < 32; ++j) { pv[j] = __expf(es[w2][h][j] - mxv); s += pv[j]; }
        float inv = 1.f / s;
#pragma unroll
        for (int j = 0; j < 32; ++j) es[w2][h][j] = pv[j] * inv;
    }
    __syncthreads();
    {   // PV: lane = output channel; V read direct from global (coalesced)
        const int h = lane >> 3;
        const float* vb = VT + (size_t)b * 2048 * 64;
        float acc = 0.f;
#pragma unroll
        for (int j = 0; j < 32; ++j)
            acc += es[w][h][j] * vb[(size_t)idxs[w][j] * 64 + lane];
        A1[pbase + lane] = acc - vsf[w][lane] + xq[w][lane];
    }
}

// ------------------------------------------------------------- BN stats -----
__global__ __launch_bounds__(256) void bn_partial_kernel(
    const float* __restrict__ Y, float* __restrict__ psum, float* __restrict__ psq)
{
    __shared__ float rs[4][64], rq[4][64];
    const int t = threadIdx.x;
    const int c = t & 63, pg = t >> 6;
    const int b = blockIdx.x >> 5;
    const int n0 = (blockIdx.x & 31) * 64;
    float s = 0.f, q = 0.f;
    for (int k = 0; k < 16; ++k) {
        float v = Y[((size_t)(b * 2048 + n0 + pg * 16 + k)) * 64 + c];
        s += v; q += v * v;
    }
    rs[pg][c] = s; rq[pg][c] = q;
    __syncthreads();
    if (t < 64) {
        psum[blockIdx.x * 64 + t] = rs[0][t] + rs[1][t] + rs[2][t] + rs[3][t];
        psq[blockIdx.x * 64 + t]  = rq[0][t] + rq[1][t] + rq[2][t] + rq[3][t];
    }
}

__global__ void bn_final_kernel(
    const float* __restrict__ psum, const float* __restrict__ psq,
    const float* __restrict__ gamma, const float* __restrict__ beta,
    float* __restrict__ sc, float* __restrict__ sh)
{
    int c = threadIdx.x;  // 64 threads
    float s = 0.f, q = 0.f;
    for (int i = 0; i < 256; ++i) { s += psum[i * 64 + c]; q += psq[i * 64 + c]; }
    float mean = s * (1.f / 16384.f);
    float var = q * (1.f / 16384.f) - mean * mean;
    float g = gamma[c] * rsqrtf(var + 1e-5f);
    sc[c] = g;
    sh[c] = beta[c] - mean * g;
}

// ------------------------------------------------------------ FFN fused -----
__global__ __launch_bounds__(256) void ffn_kernel(
    const float* __restrict__ A1, const float* __restrict__ W1,
    const float* __restrict__ W2, const float* __restrict__ s1,
    const float* __restrict__ t1, float* __restrict__ P2)
{
    __shared__ float W1s[8192];
    __shared__ float W2s[8192];
    __shared__ float xs[64][65];
    __shared__ float hs[64][129];
    __shared__ float sts[64], stt[64];
    const int t = threadIdx.x;
    const int b = blockIdx.x >> 5;
    const int n0 = (blockIdx.x & 31) * 64;
    if (t < 64) { sts[t] = s1[t]; stt[t] = t1[t]; }
    for (int i = 0; i < 32; ++i) {
        int e = t + 256 * i;
        W1s[e] = W1[e];
        W2s[e] = W2[e];
    }
    __syncthreads();
    for (int i = 0; i < 16; ++i) {
        int e = t + 256 * i, p = e >> 6, c = e & 63;
        xs[p][c] = A1[((size_t)(b * 2048 + n0 + p)) * 64 + c] * sts[c] + stt[c];
    }
    __syncthreads();
    const int p = t & 63, g = t >> 6;
    {
        float xv[64];
#pragma unroll
        for (int c = 0; c < 64; ++c) xv[c] = xs[p][c];
        for (int u = 0; u < 32; ++u) {
            int j = g * 32 + u;
            float acc = 0.f;
#pragma unroll
            for (int c = 0; c < 64; ++c) acc += W1s[j * 64 + c] * xv[c];
            hs[p][j] = (acc > 0.f) ? acc : 0.2f * acc;  // LeakyReLU 0.2
        }
    }
    __syncthreads();
    {
        float hv[128];
#pragma unroll
        for (int j = 0; j < 128; ++j) hv[j] = hs[p][j];
        const size_t pbase = ((size_t)(b * 2048 + n0 + p)) * 64 + g * 16;
        float o4[16];
#pragma unroll
        for (int oi = 0; oi < 16; ++oi) {
            int o = g * 16 + oi;
            float a = xs[p][o];  // residual x1
#pragma unroll
            for (int j = 0; j < 128; ++j) a += W2s[o * 128 + j] * hv[j];
            o4[oi] = a;
        }
#pragma unroll
        for (int q = 0; q < 4; ++q)
            *reinterpret_cast<float4*>(P2 + pbase + q * 4) =
                make_float4(o4[q * 4], o4[q * 4 + 1], o4[q * 4 + 2], o4[q * 4 + 3]);
    }
}

// ---------------------------------------------------------------- final -----
__global__ __launch_bounds__(256) void final_kernel(
    const float* __restrict__ P2, const float* __restrict__ s2,
    const float* __restrict__ t2, float* __restrict__ out)
{
    __shared__ float ts[64][65];
    __shared__ float sts[64], stt[64];
    const int t = threadIdx.x;
    const int b = blockIdx.x >> 5;
    const int n0 = (blockIdx.x & 31) * 64;
    if (t < 64) { sts[t] = s2[t]; stt[t] = t2[t]; }
    __syncthreads();
    for (int i = 0; i < 16; ++i) {
        int e = t + 256 * i, p = e >> 6, c = e & 63;
        ts[p][c] = P2[((size_t)(b * 2048 + n0 + p)) * 64 + c] * sts[c] + stt[c];
    }
    __syncthreads();
    const int c = t >> 2, p0 = (t & 3) * 16;
    float* dst = out + ((size_t)(b * 64 + c)) * 2048 + n0 + p0;
#pragma unroll
    for (int q = 0; q < 4; ++q)
        *reinterpret_cast<float4*>(dst + q * 4) =
            make_float4(ts[p0 + q * 4 + 0][c], ts[p0 + q * 4 + 1][c],
                        ts[p0 + q * 4 + 2][c], ts[p0 + q * 4 + 3][c]);
}

// ------------------------------------------------------- safe fallback ------
__global__ __launch_bounds__(256) void zero_kernel(float* __restrict__ out)
{
    reinterpret_cast<float4*>(out)[blockIdx.x * 256 + threadIdx.x] =
        make_float4(0.f, 0.f, 0.f, 0.f);  // 1024*256*16B = 4 MiB
}

// ---------------------------------------------------------------- launch ----
extern "C" void kernel_launch(void* const* d_in, const int* in_sizes, int n_in,
                              void* d_out, int out_size, void* d_ws, size_t ws_size,
                              hipStream_t stream)
{
    const float* x  = (const float*)d_in[0];
    const float* Wq = (const float*)d_in[1];
    const float* Wk = (const float*)d_in[2];
    const float* Wv = (const float*)d_in[3];
    const float* W1 = (const float*)d_in[4];
    const float* W2 = (const float*)d_in[5];
    const float* g1 = (const float*)d_in[6];
    const float* b1 = (const float*)d_in[7];
    const float* g2 = (const float*)d_in[8];
    const float* b2 = (const float*)d_in[9];
    float* out = (float*)d_out;
    (void)in_sizes; (void)n_in; (void)out_size;

    char* ws = (char*)d_ws;
    const size_t off_xx  = 0;                   // 64 KiB
    const size_t off_KT  = 65536;               // 4 MiB fp32 (P2 overlays after attn)
    const size_t off_VT  = off_KT  + 4194304;   // 4 MiB
    const size_t off_idx = off_VT  + 4194304;   // 2 MiB int (xh plane before select)
    const size_t off_A1  = off_idx + 2097152;   // 4 MiB fp32 (xm+xl planes before attn)
    const size_t off_s1  = off_A1  + 4194304;
    const size_t off_t1  = off_s1 + 256;
    const size_t off_s2  = off_t1 + 256;
    const size_t off_t2  = off_s2 + 256;
    const size_t off_Dp  = 14815232;            // key planes region, 4 KiB aligned
    const size_t KP_SZ   = (size_t)8 * 2048 * 2048 * 2;  // 64 MiB
    const size_t REQ_FAST = off_Dp + 2 * KP_SZ; // ~142.2 MiB

    if (ws_size < REQ_FAST) {  // constant per capture: safe fail
        zero_kernel<<<1024, 256, 0, stream>>>(out);
        return;
    }

    float* xx = (float*)(ws + off_xx);
    float* KT = (float*)(ws + off_KT);
    float* VT = (float*)(ws + off_VT);
    int* idx  = (int*)(ws + off_idx);
    float* A1 = (float*)(ws + off_A1);
    float* P2 = KT;  // KT dead after attn
    short* xh = (short*)(ws + off_idx);
    short* xm = (short*)(ws + off_A1);
    short* xl = (short*)(ws + off_A1 + 2097152);
    float* s1 = (float*)(ws + off_s1); float* t1 = (float*)(ws + off_t1);
    float* s2 = (float*)(ws + off_s2); float* t2 = (float*)(ws + off_t2);
    unsigned short* Kp = (unsigned short*)(ws + off_Dp);
    unsigned short* Lp = (unsigned short*)(ws + off_Dp + KP_SZ);
    float* Qp = (float*)(ws + off_Dp);   // overlays Kp (dead after select)
    float* ps1 = (float*)(ws + off_Dp);  // BN partials overlay (Qp dead post-attn)
    float* pq1 = ps1 + 16384;
    float* ps2 = ps1 + 32768;
    float* pq2 = ps1 + 49152;

    prep_kernel<<<512, 256, 0, stream>>>(x, Wk, Wv, xx, KT, VT, xh, xm, xl);
    gemm_kernel<<<2048, 256, 0, stream>>>(xh, xm, xl, xx, Kp, Lp);
    select_kernel<<<4096, 256, 0, stream>>>(Kp, Lp, idx);
    qproj_kernel<<<512, 256, 0, stream>>>(x, Wq, Qp);
    attn_kernel<<<4096, 256, 0, stream>>>(x, Qp, KT, VT, idx, A1);
    bn_partial_kernel<<<256, 256, 0, stream>>>(A1, ps1, pq1);
    bn_final_kernel<<<1, 64, 0, stream>>>(ps1, pq1, g1, b1, s1, t1);
    ffn_kernel<<<256, 256, 0, stream>>>(A1, W1, W2, s1, t1, P2);
    bn_partial_kernel<<<256, 256, 0, stream>>>(P2, ps2, pq2);
    bn_final_kernel<<<1, 64, 0, stream>>>(ps2, pq2, g2, b2, s2, t2);
    final_kernel<<<256, 256, 0, stream>>>(P2, s2, t2, out);
}

// Round 12
// 258.768 us; speedup vs baseline: 1.0617x; 1.0076x over previous
//
#include <hip/hip_runtime.h>

// B=8, C=64, N=2048, K=32, H=8, d=8. Inputs FLOAT32; output FLOAT32.
// R20 (vs R19, select ONLY changed): coalesced Kp/Lp reads — lane owns
// pos = q*512 + lane*8 + e (wave reads contiguous 1KB per instruction) vs
// R19's lane*32 pattern (16B per lane at 64B stride = 4x L1 request
// amplification; select was 44us at 885 GB/s, VALUBusy 51%). Selection
// logic, comparator, and storage layout unchanged; only lane ownership and
// pos encoding differ (set identical; orow order relaxed as since R15).
// This also blame-assigns R17's mystery failure (attn side passed in R19).

#define NN 2048

typedef __attribute__((ext_vector_type(8))) short bf16x8;
typedef __attribute__((ext_vector_type(8))) unsigned short u16x8;
typedef __attribute__((ext_vector_type(4))) float f32x4;

// Exact 3-way bf16 split of an f32 value (hi+mid+lo == x exactly).
__device__ inline void bsplit(float x, short& h, short& m, short& l)
{
    unsigned u  = __float_as_uint(x);
    unsigned hb = (u + 0x7FFFu + ((u >> 16) & 1u)) >> 16;
    float hf = __uint_as_float(hb << 16);
    float r1 = x - hf;                       // exact (Sterbenz)
    unsigned u1 = __float_as_uint(r1);
    unsigned mb = (u1 + 0x7FFFu + ((u1 >> 16) & 1u)) >> 16;
    float mf = __uint_as_float(mb << 16);
    float r2 = r1 - mf;                      // exact; <= 8 significant bits
    unsigned u2 = __float_as_uint(r2);
    unsigned lb = (u2 + 0x7FFFu + ((u2 >> 16) & 1u)) >> 16;
    h = (short)hb; m = (short)mb; l = (short)lb;
}

// ---------------------------------------------------------------- prep ------
__global__ __launch_bounds__(256) void prep_kernel(
    const float* __restrict__ x, const float* __restrict__ Wk,
    const float* __restrict__ Wv, float* __restrict__ xx,
    float* __restrict__ KT, float* __restrict__ VT,
    short* __restrict__ xh, short* __restrict__ xm, short* __restrict__ xl)
{
    __shared__ float xs[64][33];
    __shared__ float wks[4096], wvs[4096];
    const int t = threadIdx.x;
    const int b = blockIdx.x >> 6;
    const int n0 = (blockIdx.x & 63) * 32;
    for (int i = 0; i < 16; ++i) {
        int e = t + 256 * i;
        wks[e] = Wk[e];
        wvs[e] = Wv[e];
    }
    for (int i = 0; i < 8; ++i) {
        int e = t + 256 * i;
        xs[e >> 5][e & 31] = x[((size_t)b * 64 + (e >> 5)) * 2048 + n0 + (e & 31)];
    }
    __syncthreads();
    if (t < 32) {
        float s = 0.f;
#pragma unroll
        for (int c = 0; c < 64; ++c) { float v = xs[c][t]; s += v * v; }
        xx[b * 2048 + n0 + t] = s;
    }
    const int p = t & 31, g = t >> 5;
    {   // split planes: thread (p,g) -> channels [g*8, g*8+8) of point p
        u16x8 vh, vm, vl;
#pragma unroll
        for (int ci = 0; ci < 8; ++ci) {
            short h, m, l;
            bsplit(xs[g * 8 + ci][p], h, m, l);
            vh[ci] = (unsigned short)h; vm[ci] = (unsigned short)m; vl[ci] = (unsigned short)l;
        }
        size_t base = ((size_t)(b * 2048 + n0 + p)) * 64 + g * 8;
        *reinterpret_cast<u16x8*>(xh + base) = vh;
        *reinterpret_cast<u16x8*>(xm + base) = vm;
        *reinterpret_cast<u16x8*>(xl + base) = vl;
    }
    {   // K/V projections: 8 output channels per thread
        float xv[64];
#pragma unroll
        for (int c = 0; c < 64; ++c) xv[c] = xs[c][p];
        size_t base = ((size_t)(b * 2048 + n0 + p)) * 64 + g * 8;
        float ok[8], ov[8];
#pragma unroll
        for (int oi = 0; oi < 8; ++oi) {
            int o = g * 8 + oi;
            float ak = 0.f, av = 0.f;
#pragma unroll
            for (int c = 0; c < 64; ++c) {
                float xc = xv[c];
                ak += wks[o * 64 + c] * xc;
                av += wvs[o * 64 + c] * xc;
            }
            ok[oi] = ak; ov[oi] = av;
        }
        *reinterpret_cast<float4*>(KT + base)     = make_float4(ok[0], ok[1], ok[2], ok[3]);
        *reinterpret_cast<float4*>(KT + base + 4) = make_float4(ok[4], ok[5], ok[6], ok[7]);
        *reinterpret_cast<float4*>(VT + base)     = make_float4(ov[0], ov[1], ov[2], ov[3]);
        *reinterpret_cast<float4*>(VT + base + 4) = make_float4(ov[4], ov[5], ov[6], ov[7]);
    }
}

// ---------------------------------------------------------------- qproj -----
__global__ __launch_bounds__(256) void qproj_kernel(
    const float* __restrict__ x, const float* __restrict__ Wq,
    float* __restrict__ Qp)
{
    __shared__ float xs[64][33];
    __shared__ float wqs[4096];
    const int t = threadIdx.x;
    const int b = blockIdx.x >> 6;
    const int n0 = (blockIdx.x & 63) * 32;
    for (int i = 0; i < 16; ++i) { int e = t + 256 * i; wqs[e] = Wq[e]; }
    for (int i = 0; i < 8; ++i) {
        int e = t + 256 * i;
        xs[e >> 5][e & 31] = x[((size_t)b * 64 + (e >> 5)) * 2048 + n0 + (e & 31)];
    }
    __syncthreads();
    const int p = t & 31, g = t >> 5;
    float xv[64];
#pragma unroll
    for (int c = 0; c < 64; ++c) xv[c] = xs[c][p];
    size_t base = ((size_t)(b * 2048 + n0 + p)) * 64 + g * 8;
    float oq[8];
#pragma unroll
    for (int oi = 0; oi < 8; ++oi) {
        int o = g * 8 + oi;
        float a = 0.f;
#pragma unroll
        for (int c = 0; c < 64; ++c) a += wqs[o * 64 + c] * xv[c];
        oq[oi] = a * 0.35355339059327379f;
    }
    *reinterpret_cast<float4*>(Qp + base)     = make_float4(oq[0], oq[1], oq[2], oq[3]);
    *reinterpret_cast<float4*>(Qp + base + 4) = make_float4(oq[4], oq[5], oq[6], oq[7]);
}

// ------------------------------------------------------------- knn gemm -----
// D'[b][n][m] = (2*G[n][m] - xx[n]) - xx[m]; sortable u32 key stored as
// hi16 -> Kp, lo16 -> Lp at pos = c0 + rl*8 + cb (col = c0 + cb*16 + rl).
// MFMA order identical to R12: lh,hl,mm,mh,hm,hh.
__device__ inline void mm6(f32x4& a, bf16x8 Ah, bf16x8 Am, bf16x8 Al,
                           bf16x8 Bh, bf16x8 Bm, bf16x8 Bl)
{
    a = __builtin_amdgcn_mfma_f32_16x16x32_bf16(Al, Bh, a, 0, 0, 0);
    a = __builtin_amdgcn_mfma_f32_16x16x32_bf16(Ah, Bl, a, 0, 0, 0);
    a = __builtin_amdgcn_mfma_f32_16x16x32_bf16(Am, Bm, a, 0, 0, 0);
    a = __builtin_amdgcn_mfma_f32_16x16x32_bf16(Am, Bh, a, 0, 0, 0);
    a = __builtin_amdgcn_mfma_f32_16x16x32_bf16(Ah, Bm, a, 0, 0, 0);
    a = __builtin_amdgcn_mfma_f32_16x16x32_bf16(Ah, Bh, a, 0, 0, 0);
}

__global__ __launch_bounds__(256) void gemm_kernel(
    const short* __restrict__ xh, const short* __restrict__ xm,
    const short* __restrict__ xl, const float* __restrict__ xx,
    unsigned short* __restrict__ Kp, unsigned short* __restrict__ Lp)
{
    __shared__ short BhL[8192], BmL[8192], BlL[8192];  // 48 KiB
    const int t = threadIdx.x;
    const int lane = t & 63;
    const int w = t >> 6;
    const int b = blockIdx.x >> 8;
    const int tile = blockIdx.x & 255;
    const int r0 = (tile >> 4) * 128 + w * 32;
    const int c0 = (tile & 15) * 128;
    const int rl = lane & 15;
    const int g = lane >> 4;
    const int kg = g * 8;

    const size_t boff = (size_t)b * 2048 * 64;
    const short* XH = xh + boff;
    const short* XM = xm + boff;
    const short* XL = xl + boff;

    bf16x8 aH[2][2], aM[2][2], aL[2][2];
#pragma unroll
    for (int s = 0; s < 2; ++s)
#pragma unroll
        for (int rb = 0; rb < 2; ++rb) {
            const size_t ab = (size_t)(r0 + rb * 16 + rl) * 64 + s * 32 + kg;
            aH[s][rb] = *reinterpret_cast<const bf16x8*>(XH + ab);
            aM[s][rb] = *reinterpret_cast<const bf16x8*>(XM + ab);
            aL[s][rb] = *reinterpret_cast<const bf16x8*>(XL + ab);
        }

    {   // stage B panel; 16B chunk swizzle j ^= col&7
        const short* sH = XH + (size_t)c0 * 64;
        const short* sM = XM + (size_t)c0 * 64;
        const short* sL = XL + (size_t)c0 * 64;
#pragma unroll
        for (int i = 0; i < 4; ++i) {
            int ci = t + 256 * i;
            int col = ci >> 3, j = ci & 7;
            int d = col * 64 + ((j ^ (col & 7)) << 3);
            *reinterpret_cast<u16x8*>(BhL + d) = *reinterpret_cast<const u16x8*>(sH + ci * 8);
            *reinterpret_cast<u16x8*>(BmL + d) = *reinterpret_cast<const u16x8*>(sM + ci * 8);
            *reinterpret_cast<u16x8*>(BlL + d) = *reinterpret_cast<const u16x8*>(sL + ci * 8);
        }
    }
    __syncthreads();

    f32x4 acc[2][8];
#pragma unroll
    for (int rb = 0; rb < 2; ++rb)
#pragma unroll
        for (int cb = 0; cb < 8; ++cb)
            acc[rb][cb] = (f32x4){0.f, 0.f, 0.f, 0.f};

#pragma unroll
    for (int cb = 0; cb < 8; ++cb) {
        __builtin_amdgcn_sched_barrier(0);
        const int cl = cb * 16 + rl;
#pragma unroll
        for (int s = 0; s < 2; ++s) {
            const int d = cl * 64 + (((s * 4 + g) ^ (cl & 7)) << 3);
            bf16x8 Bh = *reinterpret_cast<const bf16x8*>(BhL + d);
            bf16x8 Bm = *reinterpret_cast<const bf16x8*>(BmL + d);
            bf16x8 Bl = *reinterpret_cast<const bf16x8*>(BlL + d);
            mm6(acc[0][cb], aH[s][0], aM[s][0], aL[s][0], Bh, Bm, Bl);
            mm6(acc[1][cb], aH[s][1], aM[s][1], aL[s][1], Bh, Bm, Bl);
        }
    }
    __builtin_amdgcn_sched_barrier(0);

    // epilogue: C/D layout col=lane&15, row=(lane>>4)*4+reg; store key planes
    const float* xxb = xx + b * 2048;
    const int rg = g * 4;
#pragma unroll
    for (int rb = 0; rb < 2; ++rb) {
#pragma unroll
        for (int e = 0; e < 4; ++e) {
            const int row = r0 + rb * 16 + rg + e;
            const float xn = xxb[row];
            unsigned hiw[4], low[4];
#pragma unroll
            for (int cp = 0; cp < 4; ++cp) {
                unsigned su[2];
#pragma unroll
                for (int h2 = 0; h2 < 2; ++h2) {
                    const int cb = cp * 2 + h2;
                    float v = 2.f * acc[rb][cb][e] - xn;   // (2G - xx_n)
                    v = v - xxb[c0 + cb * 16 + rl];        // ... - xx_m
                    unsigned u = __float_as_uint(v);
                    su[h2] = u ^ (unsigned)(((int)u >> 31) | 0x80000000);
                }
                hiw[cp] = (su[0] >> 16) | (su[1] & 0xFFFF0000u);
                low[cp] = (su[0] & 0xFFFFu) | (su[1] << 16);
            }
            const size_t base = ((size_t)(b * 2048 + row)) * 2048 + c0 + rl * 8;
            *reinterpret_cast<uint4*>(Kp + base) = make_uint4(hiw[0], hiw[1], hiw[2], hiw[3]);
            *reinterpret_cast<uint4*>(Lp + base) = make_uint4(low[0], low[1], low[2], low[3]);
        }
    }
}

// ------------------------------------------------------------ knn select ----
// Exact top-32 per row from hi16 plane + boundary lo16. pos -> col (fixed
// storage property): gidx = (pos & ~127) + (pos & 7)*16 + ((pos >> 3) & 15).
// Full comparator = (hi, lo, 2047-gidx) desc == (value desc, low-idx tie).
// R20: coalesced reads — lane owns pos = q*512 + lane*8 + e (slot s=q*8+e);
// pos owner lane = (pos>>3)&63, slot = ((pos>>9)<<3)|(pos&7).
__global__ __launch_bounds__(256) void select_kernel(
    const unsigned short* __restrict__ Kp, const unsigned short* __restrict__ Lp,
    int* __restrict__ idx)
{
    __shared__ unsigned cand[4][256];  // (hi<<12)|pos, 4 KiB
    const int t = threadIdx.x, w = t >> 6, lane = t & 63;
    const int b = blockIdx.x >> 9;
    const int r = (blockIdx.x & 511) * 4 + w;
    const size_t rowbase = ((size_t)(b * 2048 + r)) * 2048;
    int* orow = idx + ((size_t)(b * 2048 + r)) * 32;

    unsigned short kv[32];
#pragma unroll
    for (int q = 0; q < 4; ++q) {
        u16x8 v = *reinterpret_cast<const u16x8*>(Kp + rowbase + q * 512 + lane * 8);
#pragma unroll
        for (int e = 0; e < 8; ++e) kv[q * 8 + e] = v[e];
    }
    unsigned mx = 0;
#pragma unroll
    for (int s = 0; s < 32; ++s) mx = kv[s] > mx ? (unsigned)kv[s] : mx;
    // T = 32nd-largest per-lane max (16-bit ballot radix)
    unsigned T = 0;
#pragma unroll
    for (int bit = 15; bit >= 0; --bit) {
        unsigned c2 = T | (1u << bit);
        if (__popcll(__ballot(mx >= c2)) >= 32) T = c2;
    }
    int c = 0;
#pragma unroll
    for (int s = 0; s < 32; ++s) c += (kv[s] >= T) ? 1 : 0;
    int pfx = c;
#pragma unroll
    for (int d = 1; d < 64; d <<= 1) {
        int o = __shfl_up(pfx, d);
        pfx += (lane >= d) ? o : 0;
    }
    const int total = __shfl(pfx, 63);   // >= 32 always
    int off = pfx - c;

    if (total <= 256) {  // wave-uniform fast path (typical: ~35-60)
#pragma unroll
        for (int s = 0; s < 32; ++s) {
            if (kv[s] >= T) {
                unsigned pos = ((unsigned)(s >> 3) << 9) + (unsigned)(lane * 8) + (unsigned)(s & 7);
                cand[w][off] = ((unsigned)kv[s] << 12) | pos;
                ++off;
            }
        }
        asm volatile("s_waitcnt lgkmcnt(0)" ::: "memory");
        __builtin_amdgcn_sched_barrier(0);
        bool val[4]; unsigned hi[4], pos_[4];
#pragma unroll
        for (int s2 = 0; s2 < 4; ++s2) {
            int i2 = lane + 64 * s2;
            unsigned e2 = cand[w][i2];
            val[s2] = i2 < total;
            hi[s2] = e2 >> 12;
            pos_[s2] = e2 & 0xFFFu;
        }
        // S = 32nd-largest candidate hi
        unsigned S = 0;
#pragma unroll
        for (int bit = 15; bit >= 0; --bit) {
            unsigned c2 = S | (1u << bit);
            int cnt = 0;
#pragma unroll
            for (int s2 = 0; s2 < 4; ++s2)
                cnt += __popcll(__ballot(val[s2] && hi[s2] >= c2));
            if (cnt >= 32) S = c2;
        }
        bool isin[4], bnd[4];
        int cin = 0;
#pragma unroll
        for (int s2 = 0; s2 < 4; ++s2) {
            isin[s2] = val[s2] && hi[s2] > S;
            bnd[s2]  = val[s2] && hi[s2] == S;
            cin += __popcll(__ballot(isin[s2]));
        }
        const int need = 32 - cin;            // >= 1
        unsigned lo16[4];
#pragma unroll
        for (int s2 = 0; s2 < 4; ++s2)
            lo16[s2] = bnd[s2] ? (unsigned)Lp[rowbase + pos_[s2]] : 0u;
        // L = need-th largest lo16 among boundary
        unsigned L = 0;
#pragma unroll
        for (int bit = 15; bit >= 0; --bit) {
            unsigned c2 = L | (1u << bit);
            int cnt = 0;
#pragma unroll
            for (int s2 = 0; s2 < 4; ++s2)
                cnt += __popcll(__ballot(bnd[s2] && lo16[s2] >= c2));
            if (cnt >= need) L = c2;
        }
        bool in2[4], bnd2[4];
        int a2 = 0;
#pragma unroll
        for (int s2 = 0; s2 < 4; ++s2) {
            in2[s2]  = bnd[s2] && lo16[s2] > L;
            bnd2[s2] = bnd[s2] && lo16[s2] == L;
            a2 += __popcll(__ballot(in2[s2]));
        }
        const int need2 = need - a2;          // >= 1
        unsigned lo11[4]; int gix[4];
#pragma unroll
        for (int s2 = 0; s2 < 4; ++s2) {
            unsigned p = pos_[s2];
            gix[s2] = (int)((p & ~127u) + (p & 7u) * 16u + ((p >> 3) & 15u));
            lo11[s2] = 2047u - (unsigned)gix[s2];
        }
        unsigned L2 = 0;
#pragma unroll
        for (int bit = 10; bit >= 0; --bit) {
            unsigned c2 = L2 | (1u << bit);
            int cnt = 0;
#pragma unroll
            for (int s2 = 0; s2 < 4; ++s2)
                cnt += __popcll(__ballot(bnd2[s2] && lo11[s2] >= c2));
            if (cnt >= need2) L2 = c2;
        }
        bool sel[4]; int nsel = 0;
#pragma unroll
        for (int s2 = 0; s2 < 4; ++s2) {
            sel[s2] = isin[s2] || in2[s2] || (bnd2[s2] && lo11[s2] >= L2);
            nsel += sel[s2] ? 1 : 0;
        }
        int p2 = nsel;
#pragma unroll
        for (int d = 1; d < 64; d <<= 1) {
            int o = __shfl_up(p2, d);
            p2 += (lane >= d) ? o : 0;
        }
        int wo = p2 - nsel;
#pragma unroll
        for (int s2 = 0; s2 < 4; ++s2)
            if (sel[s2]) { orow[wo] = gix[s2]; ++wo; }
    } else {
        // exact fallback (rare): full u32 keys, masked-rescan tournament
        unsigned short lv[32];
#pragma unroll
        for (int q = 0; q < 4; ++q) {
            u16x8 v2 = *reinterpret_cast<const u16x8*>(Lp + rowbase + q * 512 + lane * 8);
#pragma unroll
            for (int e = 0; e < 8; ++e) lv[q * 8 + e] = v2[e];
        }
        unsigned ku[32], lidx[32];
#pragma unroll
        for (int s = 0; s < 32; ++s) {
            ku[s] = ((unsigned)kv[s] << 16) | (unsigned)lv[s];
            unsigned p = ((unsigned)(s >> 3) << 9) + (unsigned)(lane * 8) + (unsigned)(s & 7);
            unsigned g2 = (p & ~127u) + (p & 7u) * 16u + ((p >> 3) & 15u);
            lidx[s] = 2047u - g2;
        }
        unsigned cons = 0u;
        for (int it = 0; it < 32; ++it) {
            unsigned b2 = 0u, l2 = 0u;
#pragma unroll
            for (int s = 0; s < 32; ++s) {
                bool ok = !((cons >> s) & 1u) &&
                          ((ku[s] > b2) || (ku[s] == b2 && lidx[s] > l2));
                b2 = ok ? ku[s] : b2;
                l2 = ok ? lidx[s] : l2;
            }
            unsigned wsv = b2, wlo = l2;
#pragma unroll
            for (int d = 1; d < 64; d <<= 1) {
                unsigned osv = __shfl_xor(wsv, d);
                unsigned olo = __shfl_xor(wlo, d);
                bool take = (osv > wsv) || (osv == wsv && olo > wlo);
                wsv = take ? osv : wsv;
                wlo = take ? olo : wlo;
            }
            int g2 = 2047 - (int)wlo;
            unsigned p = (unsigned)((g2 & ~127) + (g2 & 15) * 8 + ((g2 >> 4) & 7));
            if (lane == (int)((p >> 3) & 63u)) {
                unsigned slot = ((p >> 9) << 3) | (p & 7u);
                cons |= 1u << slot;
            }
            if (lane == 0) orow[it] = g2;
        }
    }
}

// ---------------------------------------------------------------- attn ------
// 4 points/block, 1 wave/point. Energies inline during K gather; V NOT
// staged — PV reads V[nbi_j*64 + lane] straight from global (coalesced,
// L2-resident). LDS ~7.9KB -> 8 blocks/CU. (R19, unchanged.)
__global__ __launch_bounds__(256) void attn_kernel(
    const float* __restrict__ x, const float* __restrict__ Qp,
    const float* __restrict__ KT, const float* __restrict__ VT,
    const int* __restrict__ idx, float* __restrict__ A1)
{
    __shared__ float qs[4][64], xq[4][64], vsf[4][64];
    __shared__ float es[4][8][33];
    __shared__ int idxs[4][32];
    const int t = threadIdx.x, w = t >> 6, lane = t & 63;
    const int b = blockIdx.x >> 9;
    const int n = (blockIdx.x & 511) * 4 + w;
    const size_t prow = (size_t)(b * 2048 + n);
    const size_t pbase = prow * 64;

    qs[w][lane]  = Qp[pbase + lane];
    xq[w][lane]  = x[((size_t)b * 64 + lane) * 2048 + n];
    vsf[w][lane] = VT[pbase + lane];
    if (lane < 32) idxs[w][lane] = idx[prow * 32 + lane] & 2047;  // clamp
    __syncthreads();
    {   // energies: lane -> (j = lane>>1, half = lane&1)
        const int j = lane >> 1, half = lane & 1, c0 = half * 32;
        const int nbi = idxs[w][j];
        const float* kr = KT + ((size_t)(b * 2048 + nbi)) * 64 + c0;
        float eh[4] = {0.f, 0.f, 0.f, 0.f};
#pragma unroll
        for (int q = 0; q < 8; ++q) {
            float4 kq = *reinterpret_cast<const float4*>(kr + q * 4);
            float4 qv = *reinterpret_cast<const float4*>(&qs[w][c0 + q * 4]);
            const int hh = q >> 1;
            eh[hh] += qv.x * kq.x;   // d ascending: matches prior sum order
            eh[hh] += qv.y * kq.y;
            eh[hh] += qv.z * kq.z;
            eh[hh] += qv.w * kq.w;
        }
#pragma unroll
        for (int hh = 0; hh < 4; ++hh) es[w][half * 4 + hh][j] = eh[hh];
    }
    __syncthreads();
    if (t < 32) {  // serial per-head softmax (unchanged semantics)
        int w2 = t >> 3, h = t & 7;
        float mxv = -INFINITY;
#pragma unroll
        for (int j = 0; j < 32; ++j) mxv = fmaxf(mxv, es[w2][h][j]);
        float pv[32], s = 0.f;
#pragma unroll
        for (int j = 0; j < 32; ++j) { pv[j] = __expf(es[w2][h][j] - mxv); s += pv[j]; }
        float inv = 1.f / s;
#pragma unroll
        for (int j = 0; j < 32; ++j) es[w2][h][j] = pv[j] * inv;
    }
    __syncthreads();
    {   // PV: lane = output channel; V read direct from global (coalesced)
        const int h = lane >> 3;
        const float* vb = VT + (size_t)b * 2048 * 64;
        float acc = 0.f;
#pragma unroll
        for (int j = 0; j < 32; ++j)
            acc += es[w][h][j] * vb[(size_t)idxs[w][j] * 64 + lane];
        A1[pbase + lane] = acc - vsf[w][lane] + xq[w][lane];
    }
}

// ------------------------------------------------------------- BN stats -----
__global__ __launch_bounds__(256) void bn_partial_kernel(
    const float* __restrict__ Y, float* __restrict__ psum, float* __restrict__ psq)
{
    __shared__ float rs[4][64], rq[4][64];
    const int t = threadIdx.x;
    const int c = t & 63, pg = t >> 6;
    const int b = blockIdx.x >> 5;
    const int n0 = (blockIdx.x & 31) * 64;
    float s = 0.f, q = 0.f;
    for (int k = 0; k < 16; ++k) {
        float v = Y[((size_t)(b * 2048 + n0 + pg * 16 + k)) * 64 + c];
        s += v; q += v * v;
    }
    rs[pg][c] = s; rq[pg][c] = q;
    __syncthreads();
    if (t < 64) {
        psum[blockIdx.x * 64 + t] = rs[0][t] + rs[1][t] + rs[2][t] + rs[3][t];
        psq[blockIdx.x * 64 + t]  = rq[0][t] + rq[1][t] + rq[2][t] + rq[3][t];
    }
}

__global__ void bn_final_kernel(
    const float* __restrict__ psum, const float* __restrict__ psq,
    const float* __restrict__ gamma, const float* __restrict__ beta,
    float* __restrict__ sc, float* __restrict__ sh)
{
    int c = threadIdx.x;  // 64 threads
    float s = 0.f, q = 0.f;
    for (int i = 0; i < 256; ++i) { s += psum[i * 64 + c]; q += psq[i * 64 + c]; }
    float mean = s * (1.f / 16384.f);
    float var = q * (1.f / 16384.f) - mean * mean;
    float g = gamma[c] * rsqrtf(var + 1e-5f);
    sc[c] = g;
    sh[c] = beta[c] - mean * g;
}

// ------------------------------------------------------------ FFN fused -----
__global__ __launch_bounds__(256) void ffn_kernel(
    const float* __restrict__ A1, const float* __restrict__ W1,
    const float* __restrict__ W2, const float* __restrict__ s1,
    const float* __restrict__ t1, float* __restrict__ P2)
{
    __shared__ float W1s[8192];
    __shared__ float W2s[8192];
    __shared__ float xs[64][65];
    __shared__ float hs[64][129];
    __shared__ float sts[64], stt[64];
    const int t = threadIdx.x;
    const int b = blockIdx.x >> 5;
    const int n0 = (blockIdx.x & 31) * 64;
    if (t < 64) { sts[t] = s1[t]; stt[t] = t1[t]; }
    for (int i = 0; i < 32; ++i) {
        int e = t + 256 * i;
        W1s[e] = W1[e];
        W2s[e] = W2[e];
    }
    __syncthreads();
    for (int i = 0; i < 16; ++i) {
        int e = t + 256 * i, p = e >> 6, c = e & 63;
        xs[p][c] = A1[((size_t)(b * 2048 + n0 + p)) * 64 + c] * sts[c] + stt[c];
    }
    __syncthreads();
    const int p = t & 63, g = t >> 6;
    {
        float xv[64];
#pragma unroll
        for (int c = 0; c < 64; ++c) xv[c] = xs[p][c];
        for (int u = 0; u < 32; ++u) {
            int j = g * 32 + u;
            float acc = 0.f;
#pragma unroll
            for (int c = 0; c < 64; ++c) acc += W1s[j * 64 + c] * xv[c];
            hs[p][j] = (acc > 0.f) ? acc : 0.2f * acc;  // LeakyReLU 0.2
        }
    }
    __syncthreads();
    {
        float hv[128];
#pragma unroll
        for (int j = 0; j < 128; ++j) hv[j] = hs[p][j];
        const size_t pbase = ((size_t)(b * 2048 + n0 + p)) * 64 + g * 16;
        float o4[16];
#pragma unroll
        for (int oi = 0; oi < 16; ++oi) {
            int o = g * 16 + oi;
            float a = xs[p][o];  // residual x1
#pragma unroll
            for (int j = 0; j < 128; ++j) a += W2s[o * 128 + j] * hv[j];
            o4[oi] = a;
        }
#pragma unroll
        for (int q = 0; q < 4; ++q)
            *reinterpret_cast<float4*>(P2 + pbase + q * 4) =
                make_float4(o4[q * 4], o4[q * 4 + 1], o4[q * 4 + 2], o4[q * 4 + 3]);
    }
}

// ---------------------------------------------------------------- final -----
__global__ __launch_bounds__(256) void final_kernel(
    const float* __restrict__ P2, const float* __restrict__ s2,
    const float* __restrict__ t2, float* __restrict__ out)
{
    __shared__ float ts[64][65];
    __shared__ float sts[64], stt[64];
    const int t = threadIdx.x;
    const int b = blockIdx.x >> 5;
    const int n0 = (blockIdx.x & 31) * 64;
    if (t < 64) { sts[t] = s2[t]; stt[t] = t2[t]; }
    __syncthreads();
    for (int i = 0; i < 16; ++i) {
        int e = t + 256 * i, p = e >> 6, c = e & 63;
        ts[p][c] = P2[((size_t)(b * 2048 + n0 + p)) * 64 + c] * sts[c] + stt[c];
    }
    __syncthreads();
    const int c = t >> 2, p0 = (t & 3) * 16;
    float* dst = out + ((size_t)(b * 64 + c)) * 2048 + n0 + p0;
#pragma unroll
    for (int q = 0; q < 4; ++q)
        *reinterpret_cast<float4*>(dst + q * 4) =
            make_float4(ts[p0 + q * 4 + 0][c], ts[p0 + q * 4 + 1][c],
                        ts[p0 + q * 4 + 2][c], ts[p0 + q * 4 + 3][c]);
}

// ------------------------------------------------------- safe fallback ------
__global__ __launch_bounds__(256) void zero_kernel(float* __restrict__ out)
{
    reinterpret_cast<float4*>(out)[blockIdx.x * 256 + threadIdx.x] =
        make_float4(0.f, 0.f, 0.f, 0.f);  // 1024*256*16B = 4 MiB
}

// ---------------------------------------------------------------- launch ----
extern "C" void kernel_launch(void* const* d_in, const int* in_sizes, int n_in,
                              void* d_out, int out_size, void* d_ws, size_t ws_size,
                              hipStream_t stream)
{
    const float* x  = (const float*)d_in[0];
    const float* Wq = (const float*)d_in[1];
    const float* Wk = (const float*)d_in[2];
    const float* Wv = (const float*)d_in[3];
    const float* W1 = (const float*)d_in[4];
    const float* W2 = (const float*)d_in[5];
    const float* g1 = (const float*)d_in[6];
    const float* b1 = (const float*)d_in[7];
    const float* g2 = (const float*)d_in[8];
    const float* b2 = (const float*)d_in[9];
    float* out = (float*)d_out;
    (void)in_sizes; (void)n_in; (void)out_size;

    char* ws = (char*)d_ws;
    const size_t off_xx  = 0;                   // 64 KiB
    const size_t off_KT  = 65536;               // 4 MiB fp32 (P2 overlays after attn)
    const size_t off_VT  = off_KT  + 4194304;   // 4 MiB
    const size_t off_idx = off_VT  + 4194304;   // 2 MiB int (xh plane before select)
    const size_t off_A1  = off_idx + 2097152;   // 4 MiB fp32 (xm+xl planes before attn)
    const size_t off_s1  = off_A1  + 4194304;
    const size_t off_t1  = off_s1 + 256;
    const size_t off_s2  = off_t1 + 256;
    const size_t off_t2  = off_s2 + 256;
    const size_t off_Dp  = 14815232;            // key planes region, 4 KiB aligned
    const size_t KP_SZ   = (size_t)8 * 2048 * 2048 * 2;  // 64 MiB
    const size_t REQ_FAST = off_Dp + 2 * KP_SZ; // ~142.2 MiB

    if (ws_size < REQ_FAST) {  // constant per capture: safe fail
        zero_kernel<<<1024, 256, 0, stream>>>(out);
        return;
    }

    float* xx = (float*)(ws + off_xx);
    float* KT = (float*)(ws + off_KT);
    float* VT = (float*)(ws + off_VT);
    int* idx  = (int*)(ws + off_idx);
    float* A1 = (float*)(ws + off_A1);
    float* P2 = KT;  // KT dead after attn
    short* xh = (short*)(ws + off_idx);
    short* xm = (short*)(ws + off_A1);
    short* xl = (short*)(ws + off_A1 + 2097152);
    float* s1 = (float*)(ws + off_s1); float* t1 = (float*)(ws + off_t1);
    float* s2 = (float*)(ws + off_s2); float* t2 = (float*)(ws + off_t2);
    unsigned short* Kp = (unsigned short*)(ws + off_Dp);
    unsigned short* Lp = (unsigned short*)(ws + off_Dp + KP_SZ);
    float* Qp = (float*)(ws + off_Dp);   // overlays Kp (dead after select)
    float* ps1 = (float*)(ws + off_Dp);  // BN partials overlay (Qp dead post-attn)
    float* pq1 = ps1 + 16384;
    float* ps2 = ps1 + 32768;
    float* pq2 = ps1 + 49152;

    prep_kernel<<<512, 256, 0, stream>>>(x, Wk, Wv, xx, KT, VT, xh, xm, xl);
    gemm_kernel<<<2048, 256, 0, stream>>>(xh, xm, xl, xx, Kp, Lp);
    select_kernel<<<4096, 256, 0, stream>>>(Kp, Lp, idx);
    qproj_kernel<<<512, 256, 0, stream>>>(x, Wq, Qp);
    attn_kernel<<<4096, 256, 0, stream>>>(x, Qp, KT, VT, idx, A1);
    bn_partial_kernel<<<256, 256, 0, stream>>>(A1, ps1, pq1);
    bn_final_kernel<<<1, 64, 0, stream>>>(ps1, pq1, g1, b1, s1, t1);
    ffn_kernel<<<256, 256, 0, stream>>>(A1, W1, W2, s1, t1, P2);
    bn_partial_kernel<<<256, 256, 0, stream>>>(P2, ps2, pq2);
    bn_final_kernel<<<1, 64, 0, stream>>>(ps2, pq2, g2, b2, s2, t2);
    final_kernel<<<256, 256, 0, stream>>>(P2, s2, t2, out);
}

// Round 14
// 255.844 us; speedup vs baseline: 1.0738x; 1.0114x over previous
//
#include <hip/hip_runtime.h>

// B=8, C=64, N=2048, K=32, H=8, d=8. Inputs FLOAT32; output FLOAT32.
// R22: select REVERTED to R20-proven form (R17/R21 both failed a post-absmax
// harness check and both contained the NS=1 select core — frozen out).
// One safe change vs R20: bn_partial(P2) FUSED into ffn epilogue (identical
// tile mapping and bit-identical summation order -> ps2/pq2 bit-exact;
// removes one dispatch + a 4MB P2 re-read). Everything else R20-verbatim.

#define NN 2048

typedef __attribute__((ext_vector_type(8))) short bf16x8;
typedef __attribute__((ext_vector_type(8))) unsigned short u16x8;
typedef __attribute__((ext_vector_type(4))) float f32x4;

// Exact 3-way bf16 split of an f32 value (hi+mid+lo == x exactly).
__device__ inline void bsplit(float x, short& h, short& m, short& l)
{
    unsigned u  = __float_as_uint(x);
    unsigned hb = (u + 0x7FFFu + ((u >> 16) & 1u)) >> 16;
    float hf = __uint_as_float(hb << 16);
    float r1 = x - hf;                       // exact (Sterbenz)
    unsigned u1 = __float_as_uint(r1);
    unsigned mb = (u1 + 0x7FFFu + ((u1 >> 16) & 1u)) >> 16;
    float mf = __uint_as_float(mb << 16);
    float r2 = r1 - mf;                      // exact; <= 8 significant bits
    unsigned u2 = __float_as_uint(r2);
    unsigned lb = (u2 + 0x7FFFu + ((u2 >> 16) & 1u)) >> 16;
    h = (short)hb; m = (short)mb; l = (short)lb;
}

// ---------------------------------------------------------------- prep ------
__global__ __launch_bounds__(256) void prep_kernel(
    const float* __restrict__ x, const float* __restrict__ Wk,
    const float* __restrict__ Wv, float* __restrict__ xx,
    float* __restrict__ KT, float* __restrict__ VT,
    short* __restrict__ xh, short* __restrict__ xm, short* __restrict__ xl)
{
    __shared__ float xs[64][33];
    __shared__ float wks[4096], wvs[4096];
    const int t = threadIdx.x;
    const int b = blockIdx.x >> 6;
    const int n0 = (blockIdx.x & 63) * 32;
    for (int i = 0; i < 16; ++i) {
        int e = t + 256 * i;
        wks[e] = Wk[e];
        wvs[e] = Wv[e];
    }
    for (int i = 0; i < 8; ++i) {
        int e = t + 256 * i;
        xs[e >> 5][e & 31] = x[((size_t)b * 64 + (e >> 5)) * 2048 + n0 + (e & 31)];
    }
    __syncthreads();
    if (t < 32) {
        float s = 0.f;
#pragma unroll
        for (int c = 0; c < 64; ++c) { float v = xs[c][t]; s += v * v; }
        xx[b * 2048 + n0 + t] = s;
    }
    const int p = t & 31, g = t >> 5;
    {   // split planes: thread (p,g) -> channels [g*8, g*8+8) of point p
        u16x8 vh, vm, vl;
#pragma unroll
        for (int ci = 0; ci < 8; ++ci) {
            short h, m, l;
            bsplit(xs[g * 8 + ci][p], h, m, l);
            vh[ci] = (unsigned short)h; vm[ci] = (unsigned short)m; vl[ci] = (unsigned short)l;
        }
        size_t base = ((size_t)(b * 2048 + n0 + p)) * 64 + g * 8;
        *reinterpret_cast<u16x8*>(xh + base) = vh;
        *reinterpret_cast<u16x8*>(xm + base) = vm;
        *reinterpret_cast<u16x8*>(xl + base) = vl;
    }
    {   // K/V projections: 8 output channels per thread
        float xv[64];
#pragma unroll
        for (int c = 0; c < 64; ++c) xv[c] = xs[c][p];
        size_t base = ((size_t)(b * 2048 + n0 + p)) * 64 + g * 8;
        float ok[8], ov[8];
#pragma unroll
        for (int oi = 0; oi < 8; ++oi) {
            int o = g * 8 + oi;
            float ak = 0.f, av = 0.f;
#pragma unroll
            for (int c = 0; c < 64; ++c) {
                float xc = xv[c];
                ak += wks[o * 64 + c] * xc;
                av += wvs[o * 64 + c] * xc;
            }
            ok[oi] = ak; ov[oi] = av;
        }
        *reinterpret_cast<float4*>(KT + base)     = make_float4(ok[0], ok[1], ok[2], ok[3]);
        *reinterpret_cast<float4*>(KT + base + 4) = make_float4(ok[4], ok[5], ok[6], ok[7]);
        *reinterpret_cast<float4*>(VT + base)     = make_float4(ov[0], ov[1], ov[2], ov[3]);
        *reinterpret_cast<float4*>(VT + base + 4) = make_float4(ov[4], ov[5], ov[6], ov[7]);
    }
}

// ---------------------------------------------------------------- qproj -----
__global__ __launch_bounds__(256) void qproj_kernel(
    const float* __restrict__ x, const float* __restrict__ Wq,
    float* __restrict__ Qp)
{
    __shared__ float xs[64][33];
    __shared__ float wqs[4096];
    const int t = threadIdx.x;
    const int b = blockIdx.x >> 6;
    const int n0 = (blockIdx.x & 63) * 32;
    for (int i = 0; i < 16; ++i) { int e = t + 256 * i; wqs[e] = Wq[e]; }
    for (int i = 0; i < 8; ++i) {
        int e = t + 256 * i;
        xs[e >> 5][e & 31] = x[((size_t)b * 64 + (e >> 5)) * 2048 + n0 + (e & 31)];
    }
    __syncthreads();
    const int p = t & 31, g = t >> 5;
    float xv[64];
#pragma unroll
    for (int c = 0; c < 64; ++c) xv[c] = xs[c][p];
    size_t base = ((size_t)(b * 2048 + n0 + p)) * 64 + g * 8;
    float oq[8];
#pragma unroll
    for (int oi = 0; oi < 8; ++oi) {
        int o = g * 8 + oi;
        float a = 0.f;
#pragma unroll
        for (int c = 0; c < 64; ++c) a += wqs[o * 64 + c] * xv[c];
        oq[oi] = a * 0.35355339059327379f;
    }
    *reinterpret_cast<float4*>(Qp + base)     = make_float4(oq[0], oq[1], oq[2], oq[3]);
    *reinterpret_cast<float4*>(Qp + base + 4) = make_float4(oq[4], oq[5], oq[6], oq[7]);
}

// ------------------------------------------------------------- knn gemm -----
// D'[b][n][m] = (2*G[n][m] - xx[n]) - xx[m]; sortable u32 key stored as
// hi16 -> Kp, lo16 -> Lp at pos = c0 + rl*8 + cb (col = c0 + cb*16 + rl).
// MFMA order identical to R12: lh,hl,mm,mh,hm,hh.
__device__ inline void mm6(f32x4& a, bf16x8 Ah, bf16x8 Am, bf16x8 Al,
                           bf16x8 Bh, bf16x8 Bm, bf16x8 Bl)
{
    a = __builtin_amdgcn_mfma_f32_16x16x32_bf16(Al, Bh, a, 0, 0, 0);
    a = __builtin_amdgcn_mfma_f32_16x16x32_bf16(Ah, Bl, a, 0, 0, 0);
    a = __builtin_amdgcn_mfma_f32_16x16x32_bf16(Am, Bm, a, 0, 0, 0);
    a = __builtin_amdgcn_mfma_f32_16x16x32_bf16(Am, Bh, a, 0, 0, 0);
    a = __builtin_amdgcn_mfma_f32_16x16x32_bf16(Ah, Bm, a, 0, 0, 0);
    a = __builtin_amdgcn_mfma_f32_16x16x32_bf16(Ah, Bh, a, 0, 0, 0);
}

__global__ __launch_bounds__(256) void gemm_kernel(
    const short* __restrict__ xh, const short* __restrict__ xm,
    const short* __restrict__ xl, const float* __restrict__ xx,
    unsigned short* __restrict__ Kp, unsigned short* __restrict__ Lp)
{
    __shared__ short BhL[8192], BmL[8192], BlL[8192];  // 48 KiB
    const int t = threadIdx.x;
    const int lane = t & 63;
    const int w = t >> 6;
    const int b = blockIdx.x >> 8;
    const int tile = blockIdx.x & 255;
    const int r0 = (tile >> 4) * 128 + w * 32;
    const int c0 = (tile & 15) * 128;
    const int rl = lane & 15;
    const int g = lane >> 4;
    const int kg = g * 8;

    const size_t boff = (size_t)b * 2048 * 64;
    const short* XH = xh + boff;
    const short* XM = xm + boff;
    const short* XL = xl + boff;

    bf16x8 aH[2][2], aM[2][2], aL[2][2];
#pragma unroll
    for (int s = 0; s < 2; ++s)
#pragma unroll
        for (int rb = 0; rb < 2; ++rb) {
            const size_t ab = (size_t)(r0 + rb * 16 + rl) * 64 + s * 32 + kg;
            aH[s][rb] = *reinterpret_cast<const bf16x8*>(XH + ab);
            aM[s][rb] = *reinterpret_cast<const bf16x8*>(XM + ab);
            aL[s][rb] = *reinterpret_cast<const bf16x8*>(XL + ab);
        }

    {   // stage B panel; 16B chunk swizzle j ^= col&7
        const short* sH = XH + (size_t)c0 * 64;
        const short* sM = XM + (size_t)c0 * 64;
        const short* sL = XL + (size_t)c0 * 64;
#pragma unroll
        for (int i = 0; i < 4; ++i) {
            int ci = t + 256 * i;
            int col = ci >> 3, j = ci & 7;
            int d = col * 64 + ((j ^ (col & 7)) << 3);
            *reinterpret_cast<u16x8*>(BhL + d) = *reinterpret_cast<const u16x8*>(sH + ci * 8);
            *reinterpret_cast<u16x8*>(BmL + d) = *reinterpret_cast<const u16x8*>(sM + ci * 8);
            *reinterpret_cast<u16x8*>(BlL + d) = *reinterpret_cast<const u16x8*>(sL + ci * 8);
        }
    }
    __syncthreads();

    f32x4 acc[2][8];
#pragma unroll
    for (int rb = 0; rb < 2; ++rb)
#pragma unroll
        for (int cb = 0; cb < 8; ++cb)
            acc[rb][cb] = (f32x4){0.f, 0.f, 0.f, 0.f};

#pragma unroll
    for (int cb = 0; cb < 8; ++cb) {
        __builtin_amdgcn_sched_barrier(0);
        const int cl = cb * 16 + rl;
#pragma unroll
        for (int s = 0; s < 2; ++s) {
            const int d = cl * 64 + (((s * 4 + g) ^ (cl & 7)) << 3);
            bf16x8 Bh = *reinterpret_cast<const bf16x8*>(BhL + d);
            bf16x8 Bm = *reinterpret_cast<const bf16x8*>(BmL + d);
            bf16x8 Bl = *reinterpret_cast<const bf16x8*>(BlL + d);
            mm6(acc[0][cb], aH[s][0], aM[s][0], aL[s][0], Bh, Bm, Bl);
            mm6(acc[1][cb], aH[s][1], aM[s][1], aL[s][1], Bh, Bm, Bl);
        }
    }
    __builtin_amdgcn_sched_barrier(0);

    // epilogue: C/D layout col=lane&15, row=(lane>>4)*4+reg; store key planes
    const float* xxb = xx + b * 2048;
    const int rg = g * 4;
#pragma unroll
    for (int rb = 0; rb < 2; ++rb) {
#pragma unroll
        for (int e = 0; e < 4; ++e) {
            const int row = r0 + rb * 16 + rg + e;
            const float xn = xxb[row];
            unsigned hiw[4], low[4];
#pragma unroll
            for (int cp = 0; cp < 4; ++cp) {
                unsigned su[2];
#pragma unroll
                for (int h2 = 0; h2 < 2; ++h2) {
                    const int cb = cp * 2 + h2;
                    float v = 2.f * acc[rb][cb][e] - xn;   // (2G - xx_n)
                    v = v - xxb[c0 + cb * 16 + rl];        // ... - xx_m
                    unsigned u = __float_as_uint(v);
                    su[h2] = u ^ (unsigned)(((int)u >> 31) | 0x80000000);
                }
                hiw[cp] = (su[0] >> 16) | (su[1] & 0xFFFF0000u);
                low[cp] = (su[0] & 0xFFFFu) | (su[1] << 16);
            }
            const size_t base = ((size_t)(b * 2048 + row)) * 2048 + c0 + rl * 8;
            *reinterpret_cast<uint4*>(Kp + base) = make_uint4(hiw[0], hiw[1], hiw[2], hiw[3]);
            *reinterpret_cast<uint4*>(Lp + base) = make_uint4(low[0], low[1], low[2], low[3]);
        }
    }
}

// ------------------------------------------------------------ knn select ----
// R20-proven form (frozen). Exact top-32 per row from hi16 plane + boundary
// lo16. pos -> col: gidx = (pos & ~127) + (pos & 7)*16 + ((pos >> 3) & 15).
// Full comparator = (hi, lo, 2047-gidx) desc == (value desc, low-idx tie).
__global__ __launch_bounds__(256) void select_kernel(
    const unsigned short* __restrict__ Kp, const unsigned short* __restrict__ Lp,
    int* __restrict__ idx)
{
    __shared__ unsigned cand[4][256];  // (hi<<12)|pos, 4 KiB
    const int t = threadIdx.x, w = t >> 6, lane = t & 63;
    const int b = blockIdx.x >> 9;
    const int r = (blockIdx.x & 511) * 4 + w;
    const size_t rowbase = ((size_t)(b * 2048 + r)) * 2048;
    int* orow = idx + ((size_t)(b * 2048 + r)) * 32;

    unsigned short kv[32];
#pragma unroll
    for (int q = 0; q < 4; ++q) {
        u16x8 v = *reinterpret_cast<const u16x8*>(Kp + rowbase + q * 512 + lane * 8);
#pragma unroll
        for (int e = 0; e < 8; ++e) kv[q * 8 + e] = v[e];
    }
    unsigned mx = 0;
#pragma unroll
    for (int s = 0; s < 32; ++s) mx = kv[s] > mx ? (unsigned)kv[s] : mx;
    // T = 32nd-largest per-lane max (16-bit ballot radix)
    unsigned T = 0;
#pragma unroll
    for (int bit = 15; bit >= 0; --bit) {
        unsigned c2 = T | (1u << bit);
        if (__popcll(__ballot(mx >= c2)) >= 32) T = c2;
    }
    int c = 0;
#pragma unroll
    for (int s = 0; s < 32; ++s) c += (kv[s] >= T) ? 1 : 0;
    int pfx = c;
#pragma unroll
    for (int d = 1; d < 64; d <<= 1) {
        int o = __shfl_up(pfx, d);
        pfx += (lane >= d) ? o : 0;
    }
    const int total = __shfl(pfx, 63);   // >= 32 always
    int off = pfx - c;

    if (total <= 256) {  // wave-uniform fast path (typical: ~35-60)
#pragma unroll
        for (int s = 0; s < 32; ++s) {
            if (kv[s] >= T) {
                unsigned pos = ((unsigned)(s >> 3) << 9) + (unsigned)(lane * 8) + (unsigned)(s & 7);
                cand[w][off] = ((unsigned)kv[s] << 12) | pos;
                ++off;
            }
        }
        asm volatile("s_waitcnt lgkmcnt(0)" ::: "memory");
        __builtin_amdgcn_sched_barrier(0);
        bool val[4]; unsigned hi[4], pos_[4];
#pragma unroll
        for (int s2 = 0; s2 < 4; ++s2) {
            int i2 = lane + 64 * s2;
            unsigned e2 = cand[w][i2];
            val[s2] = i2 < total;
            hi[s2] = e2 >> 12;
            pos_[s2] = e2 & 0xFFFu;
        }
        // S = 32nd-largest candidate hi
        unsigned S = 0;
#pragma unroll
        for (int bit = 15; bit >= 0; --bit) {
            unsigned c2 = S | (1u << bit);
            int cnt = 0;
#pragma unroll
            for (int s2 = 0; s2 < 4; ++s2)
                cnt += __popcll(__ballot(val[s2] && hi[s2] >= c2));
            if (cnt >= 32) S = c2;
        }
        bool isin[4], bnd[4];
        int cin = 0;
#pragma unroll
        for (int s2 = 0; s2 < 4; ++s2) {
            isin[s2] = val[s2] && hi[s2] > S;
            bnd[s2]  = val[s2] && hi[s2] == S;
            cin += __popcll(__ballot(isin[s2]));
        }
        const int need = 32 - cin;            // >= 1
        unsigned lo16[4];
#pragma unroll
        for (int s2 = 0; s2 < 4; ++s2)
            lo16[s2] = bnd[s2] ? (unsigned)Lp[rowbase + pos_[s2]] : 0u;
        // L = need-th largest lo16 among boundary
        unsigned L = 0;
#pragma unroll
        for (int bit = 15; bit >= 0; --bit) {
            unsigned c2 = L | (1u << bit);
            int cnt = 0;
#pragma unroll
            for (int s2 = 0; s2 < 4; ++s2)
                cnt += __popcll(__ballot(bnd[s2] && lo16[s2] >= c2));
            if (cnt >= need) L = c2;
        }
        bool in2[4], bnd2[4];
        int a2 = 0;
#pragma unroll
        for (int s2 = 0; s2 < 4; ++s2) {
            in2[s2]  = bnd[s2] && lo16[s2] > L;
            bnd2[s2] = bnd[s2] && lo16[s2] == L;
            a2 += __popcll(__ballot(in2[s2]));
        }
        const int need2 = need - a2;          // >= 1
        unsigned lo11[4]; int gix[4];
#pragma unroll
        for (int s2 = 0; s2 < 4; ++s2) {
            unsigned p = pos_[s2];
            gix[s2] = (int)((p & ~127u) + (p & 7u) * 16u + ((p >> 3) & 15u));
            lo11[s2] = 2047u - (unsigned)gix[s2];
        }
        unsigned L2 = 0;
#pragma unroll
        for (int bit = 10; bit >= 0; --bit) {
            unsigned c2 = L2 | (1u << bit);
            int cnt = 0;
#pragma unroll
            for (int s2 = 0; s2 < 4; ++s2)
                cnt += __popcll(__ballot(bnd2[s2] && lo11[s2] >= c2));
            if (cnt >= need2) L2 = c2;
        }
        bool sel[4]; int nsel = 0;
#pragma unroll
        for (int s2 = 0; s2 < 4; ++s2) {
            sel[s2] = isin[s2] || in2[s2] || (bnd2[s2] && lo11[s2] >= L2);
            nsel += sel[s2] ? 1 : 0;
        }
        int p2 = nsel;
#pragma unroll
        for (int d = 1; d < 64; d <<= 1) {
            int o = __shfl_up(p2, d);
            p2 += (lane >= d) ? o : 0;
        }
        int wo = p2 - nsel;
#pragma unroll
        for (int s2 = 0; s2 < 4; ++s2)
            if (sel[s2]) { orow[wo] = gix[s2]; ++wo; }
    } else {
        // exact fallback (rare): full u32 keys, masked-rescan tournament
        unsigned short lv[32];
#pragma unroll
        for (int q = 0; q < 4; ++q) {
            u16x8 v2 = *reinterpret_cast<const u16x8*>(Lp + rowbase + q * 512 + lane * 8);
#pragma unroll
            for (int e = 0; e < 8; ++e) lv[q * 8 + e] = v2[e];
        }
        unsigned ku[32], lidx[32];
#pragma unroll
        for (int s = 0; s < 32; ++s) {
            ku[s] = ((unsigned)kv[s] << 16) | (unsigned)lv[s];
            unsigned p = ((unsigned)(s >> 3) << 9) + (unsigned)(lane * 8) + (unsigned)(s & 7);
            unsigned g2 = (p & ~127u) + (p & 7u) * 16u + ((p >> 3) & 15u);
            lidx[s] = 2047u - g2;
        }
        unsigned cons = 0u;
        for (int it = 0; it < 32; ++it) {
            unsigned b2 = 0u, l2 = 0u;
#pragma unroll
            for (int s = 0; s < 32; ++s) {
                bool ok = !((cons >> s) & 1u) &&
                          ((ku[s] > b2) || (ku[s] == b2 && lidx[s] > l2));
                b2 = ok ? ku[s] : b2;
                l2 = ok ? lidx[s] : l2;
            }
            unsigned wsv = b2, wlo = l2;
#pragma unroll
            for (int d = 1; d < 64; d <<= 1) {
                unsigned osv = __shfl_xor(wsv, d);
                unsigned olo = __shfl_xor(wlo, d);
                bool take = (osv > wsv) || (osv == wsv && olo > wlo);
                wsv = take ? osv : wsv;
                wlo = take ? olo : wlo;
            }
            int g2 = 2047 - (int)wlo;
            unsigned p = (unsigned)((g2 & ~127) + (g2 & 15) * 8 + ((g2 >> 4) & 7));
            if (lane == (int)((p >> 3) & 63u)) {
                unsigned slot = ((p >> 9) << 3) | (p & 7u);
                cons |= 1u << slot;
            }
            if (lane == 0) orow[it] = g2;
        }
    }
}

// ---------------------------------------------------------------- attn ------
// 4 points/block, 1 wave/point. Energies inline during K gather; V NOT
// staged — PV reads V[nbi_j*64 + lane] straight from global (coalesced,
// L2-resident). LDS ~7.9KB -> 8 blocks/CU. (R19, unchanged.)
__global__ __launch_bounds__(256) void attn_kernel(
    const float* __restrict__ x, const float* __restrict__ Qp,
    const float* __restrict__ KT, const float* __restrict__ VT,
    const int* __restrict__ idx, float* __restrict__ A1)
{
    __shared__ float qs[4][64], xq[4][64], vsf[4][64];
    __shared__ float es[4][8][33];
    __shared__ int idxs[4][32];
    const int t = threadIdx.x, w = t >> 6, lane = t & 63;
    const int b = blockIdx.x >> 9;
    const int n = (blockIdx.x & 511) * 4 + w;
    const size_t prow = (size_t)(b * 2048 + n);
    const size_t pbase = prow * 64;

    qs[w][lane]  = Qp[pbase + lane];
    xq[w][lane]  = x[((size_t)b * 64 + lane) * 2048 + n];
    vsf[w][lane] = VT[pbase + lane];
    if (lane < 32) idxs[w][lane] = idx[prow * 32 + lane] & 2047;  // clamp
    __syncthreads();
    {   // energies: lane -> (j = lane>>1, half = lane&1)
        const int j = lane >> 1, half = lane & 1, c0 = half * 32;
        const int nbi = idxs[w][j];
        const float* kr = KT + ((size_t)(b * 2048 + nbi)) * 64 + c0;
        float eh[4] = {0.f, 0.f, 0.f, 0.f};
#pragma unroll
        for (int q = 0; q < 8; ++q) {
            float4 kq = *reinterpret_cast<const float4*>(kr + q * 4);
            float4 qv = *reinterpret_cast<const float4*>(&qs[w][c0 + q * 4]);
            const int hh = q >> 1;
            eh[hh] += qv.x * kq.x;   // d ascending: matches prior sum order
            eh[hh] += qv.y * kq.y;
            eh[hh] += qv.z * kq.z;
            eh[hh] += qv.w * kq.w;
        }
#pragma unroll
        for (int hh = 0; hh < 4; ++hh) es[w][half * 4 + hh][j] = eh[hh];
    }
    __syncthreads();
    if (t < 32) {  // serial per-head softmax (unchanged semantics)
        int w2 = t >> 3, h = t & 7;
        float mxv = -INFINITY;
#pragma unroll
        for (int j = 0; j < 32; ++j) mxv = fmaxf(mxv, es[w2][h][j]);
        float pv[32], s = 0.f;
#pragma unroll
        for (int j = 0; j < 32; ++j) { pv[j] = __expf(es[w2][h][j] - mxv); s += pv[j]; }
        float inv = 1.f / s;
#pragma unroll
        for (int j = 0; j < 32; ++j) es[w2][h][j] = pv[j] * inv;
    }
    __syncthreads();
    {   // PV: lane = output channel; V read direct from global (coalesced)
        const int h = lane >> 3;
        const float* vb = VT + (size_t)b * 2048 * 64;
        float acc = 0.f;
#pragma unroll
        for (int j = 0; j < 32; ++j)
            acc += es[w][h][j] * vb[(size_t)idxs[w][j] * 64 + lane];
        A1[pbase + lane] = acc - vsf[w][lane] + xq[w][lane];
    }
}

// ------------------------------------------------------------- BN stats -----
__global__ __launch_bounds__(256) void bn_partial_kernel(
    const float* __restrict__ Y, float* __restrict__ psum, float* __restrict__ psq)
{
    __shared__ float rs[4][64], rq[4][64];
    const int t = threadIdx.x;
    const int c = t & 63, pg = t >> 6;
    const int b = blockIdx.x >> 5;
    const int n0 = (blockIdx.x & 31) * 64;
    float s = 0.f, q = 0.f;
    for (int k = 0; k < 16; ++k) {
        float v = Y[((size_t)(b * 2048 + n0 + pg * 16 + k)) * 64 + c];
        s += v; q += v * v;
    }
    rs[pg][c] = s; rq[pg][c] = q;
    __syncthreads();
    if (t < 64) {
        psum[blockIdx.x * 64 + t] = rs[0][t] + rs[1][t] + rs[2][t] + rs[3][t];
        psq[blockIdx.x * 64 + t]  = rq[0][t] + rq[1][t] + rq[2][t] + rq[3][t];
    }
}

__global__ void bn_final_kernel(
    const float* __restrict__ psum, const float* __restrict__ psq,
    const float* __restrict__ gamma, const float* __restrict__ beta,
    float* __restrict__ sc, float* __restrict__ sh)
{
    int c = threadIdx.x;  // 64 threads
    float s = 0.f, q = 0.f;
    for (int i = 0; i < 256; ++i) { s += psum[i * 64 + c]; q += psq[i * 64 + c]; }
    float mean = s * (1.f / 16384.f);
    float var = q * (1.f / 16384.f) - mean * mean;
    float g = gamma[c] * rsqrtf(var + 1e-5f);
    sc[c] = g;
    sh[c] = beta[c] - mean * g;
}

// ------------------------------------------------------------ FFN fused -----
// Per 64-point tile: x1 = BN1(A1) -> h = leaky(W1@x1) -> P2 = x1 + W2@h.
// R22: also emits BN2 partials (ps2/pq2) for this tile, with summation order
// bit-identical to bn_partial_kernel (k ascending per pg, then rs[0..3]).
__global__ __launch_bounds__(256) void ffn_kernel(
    const float* __restrict__ A1, const float* __restrict__ W1,
    const float* __restrict__ W2, const float* __restrict__ s1,
    const float* __restrict__ t1, float* __restrict__ P2,
    float* __restrict__ psum, float* __restrict__ psq)
{
    __shared__ float W1s[8192];
    __shared__ float W2s[8192];
    __shared__ float xs[64][65];
    __shared__ float hs[64][129];
    __shared__ float sts[64], stt[64];
    __shared__ float rs[4][64], rq[4][64];
    const int t = threadIdx.x;
    const int b = blockIdx.x >> 5;
    const int n0 = (blockIdx.x & 31) * 64;
    if (t < 64) { sts[t] = s1[t]; stt[t] = t1[t]; }
    for (int i = 0; i < 32; ++i) {
        int e = t + 256 * i;
        W1s[e] = W1[e];
        W2s[e] = W2[e];
    }
    __syncthreads();
    for (int i = 0; i < 16; ++i) {
        int e = t + 256 * i, p = e >> 6, c = e & 63;
        xs[p][c] = A1[((size_t)(b * 2048 + n0 + p)) * 64 + c] * sts[c] + stt[c];
    }
    __syncthreads();
    const int p = t & 63, g = t >> 6;
    {   // h: 32 channels per thread
        float xv[64];
#pragma unroll
        for (int c = 0; c < 64; ++c) xv[c] = xs[p][c];
        for (int u = 0; u < 32; ++u) {
            int j = g * 32 + u;
            float acc = 0.f;
#pragma unroll
            for (int c = 0; c < 64; ++c) acc += W1s[j * 64 + c] * xv[c];
            hs[p][j] = (acc > 0.f) ? acc : 0.2f * acc;  // LeakyReLU 0.2
        }
    }
    __syncthreads();
    {   // P2: 16 channels per thread; write-back into xs rows for BN stats
        float hv[128];
#pragma unroll
        for (int j = 0; j < 128; ++j) hv[j] = hs[p][j];
        const size_t pbase = ((size_t)(b * 2048 + n0 + p)) * 64 + g * 16;
        float o4[16];
#pragma unroll
        for (int oi = 0; oi < 16; ++oi) {
            int o = g * 16 + oi;
            float a = xs[p][o];  // residual x1
#pragma unroll
            for (int j = 0; j < 128; ++j) a += W2s[o * 128 + j] * hv[j];
            o4[oi] = a;
        }
#pragma unroll
        for (int q = 0; q < 4; ++q)
            *reinterpret_cast<float4*>(P2 + pbase + q * 4) =
                make_float4(o4[q * 4], o4[q * 4 + 1], o4[q * 4 + 2], o4[q * 4 + 3]);
        // stash P2 tile into xs (this thread owns xs[p][g*16..g*16+16);
        // all its reads of those slots are complete)
#pragma unroll
        for (int oi = 0; oi < 16; ++oi) xs[p][g * 16 + oi] = o4[oi];
    }
    __syncthreads();
    {   // BN2 partials, bit-identical order to bn_partial_kernel
        const int c = t & 63, pg = t >> 6;
        float s = 0.f, q = 0.f;
        for (int k = 0; k < 16; ++k) {
            float v = xs[pg * 16 + k][c];
            s += v; q += v * v;
        }
        rs[pg][c] = s; rq[pg][c] = q;
    }
    __syncthreads();
    if (t < 64) {
        psum[blockIdx.x * 64 + t] = rs[0][t] + rs[1][t] + rs[2][t] + rs[3][t];
        psq[blockIdx.x * 64 + t]  = rq[0][t] + rq[1][t] + rq[2][t] + rq[3][t];
    }
}

// ---------------------------------------------------------------- final -----
__global__ __launch_bounds__(256) void final_kernel(
    const float* __restrict__ P2, const float* __restrict__ s2,
    const float* __restrict__ t2, float* __restrict__ out)
{
    __shared__ float ts[64][65];
    __shared__ float sts[64], stt[64];
    const int t = threadIdx.x;
    const int b = blockIdx.x >> 5;
    const int n0 = (blockIdx.x & 31) * 64;
    if (t < 64) { sts[t] = s2[t]; stt[t] = t2[t]; }
    __syncthreads();
    for (int i = 0; i < 16; ++i) {
        int e = t + 256 * i, p = e >> 6, c = e & 63;
        ts[p][c] = P2[((size_t)(b * 2048 + n0 + p)) * 64 + c] * sts[c] + stt[c];
    }
    __syncthreads();
    const int c = t >> 2, p0 = (t & 3) * 16;
    float* dst = out + ((size_t)(b * 64 + c)) * 2048 + n0 + p0;
#pragma unroll
    for (int q = 0; q < 4; ++q)
        *reinterpret_cast<float4*>(dst + q * 4) =
            make_float4(ts[p0 + q * 4 + 0][c], ts[p0 + q * 4 + 1][c],
                        ts[p0 + q * 4 + 2][c], ts[p0 + q * 4 + 3][c]);
}

// ------------------------------------------------------- safe fallback ------
__global__ __launch_bounds__(256) void zero_kernel(float* __restrict__ out)
{
    reinterpret_cast<float4*>(out)[blockIdx.x * 256 + threadIdx.x] =
        make_float4(0.f, 0.f, 0.f, 0.f);  // 1024*256*16B = 4 MiB
}

// ---------------------------------------------------------------- launch ----
extern "C" void kernel_launch(void* const* d_in, const int* in_sizes, int n_in,
                              void* d_out, int out_size, void* d_ws, size_t ws_size,
                              hipStream_t stream)
{
    const float* x  = (const float*)d_in[0];
    const float* Wq = (const float*)d_in[1];
    const float* Wk = (const float*)d_in[2];
    const float* Wv = (const float*)d_in[3];
    const float* W1 = (const float*)d_in[4];
    const float* W2 = (const float*)d_in[5];
    const float* g1 = (const float*)d_in[6];
    const float* b1 = (const float*)d_in[7];
    const float* g2 = (const float*)d_in[8];
    const float* b2 = (const float*)d_in[9];
    float* out = (float*)d_out;
    (void)in_sizes; (void)n_in; (void)out_size;

    char* ws = (char*)d_ws;
    const size_t off_xx  = 0;                   // 64 KiB
    const size_t off_KT  = 65536;               // 4 MiB fp32 (P2 overlays after attn)
    const size_t off_VT  = off_KT  + 4194304;   // 4 MiB
    const size_t off_idx = off_VT  + 4194304;   // 2 MiB int (xh plane before select)
    const size_t off_A1  = off_idx + 2097152;   // 4 MiB fp32 (xm+xl planes before attn)
    const size_t off_s1  = off_A1  + 4194304;
    const size_t off_t1  = off_s1 + 256;
    const size_t off_s2  = off_t1 + 256;
    const size_t off_t2  = off_s2 + 256;
    const size_t off_Dp  = 14815232;            // key planes region, 4 KiB aligned
    const size_t KP_SZ   = (size_t)8 * 2048 * 2048 * 2;  // 64 MiB
    const size_t REQ_FAST = off_Dp + 2 * KP_SZ; // ~142.2 MiB

    if (ws_size < REQ_FAST) {  // constant per capture: safe fail
        zero_kernel<<<1024, 256, 0, stream>>>(out);
        return;
    }

    float* xx = (float*)(ws + off_xx);
    float* KT = (float*)(ws + off_KT);
    float* VT = (float*)(ws + off_VT);
    int* idx  = (int*)(ws + off_idx);
    float* A1 = (float*)(ws + off_A1);
    float* P2 = KT;  // KT dead after attn
    short* xh = (short*)(ws + off_idx);
    short* xm = (short*)(ws + off_A1);
    short* xl = (short*)(ws + off_A1 + 2097152);
    float* s1 = (float*)(ws + off_s1); float* t1 = (float*)(ws + off_t1);
    float* s2 = (float*)(ws + off_s2); float* t2 = (float*)(ws + off_t2);
    unsigned short* Kp = (unsigned short*)(ws + off_Dp);
    unsigned short* Lp = (unsigned short*)(ws + off_Dp + KP_SZ);
    float* Qp = (float*)(ws + off_Dp);   // overlays Kp (dead after select)
    float* ps1 = (float*)(ws + off_Dp);  // BN partials overlay (Qp dead post-attn)
    float* pq1 = ps1 + 16384;
    float* ps2 = ps1 + 32768;
    float* pq2 = ps1 + 49152;

    prep_kernel<<<512, 256, 0, stream>>>(x, Wk, Wv, xx, KT, VT, xh, xm, xl);
    gemm_kernel<<<2048, 256, 0, stream>>>(xh, xm, xl, xx, Kp, Lp);
    select_kernel<<<4096, 256, 0, stream>>>(Kp, Lp, idx);
    qproj_kernel<<<512, 256, 0, stream>>>(x, Wq, Qp);
    attn_kernel<<<4096, 256, 0, stream>>>(x, Qp, KT, VT, idx, A1);
    bn_partial_kernel<<<256, 256, 0, stream>>>(A1, ps1, pq1);
    bn_final_kernel<<<1, 64, 0, stream>>>(ps1, pq1, g1, b1, s1, t1);
    ffn_kernel<<<256, 256, 0, stream>>>(A1, W1, W2, s1, t1, P2, ps2, pq2);
    bn_final_kernel<<<1, 64, 0, stream>>>(ps2, pq2, g2, b2, s2, t2);
    final_kernel<<<256, 256, 0, stream>>>(P2, s2, t2, out);
}